// Round 11
// baseline (243.943 us; speedup 1.0000x reference)
//
#include <hip/hip_runtime.h>
#include <hip/hip_bf16.h>

#define T_TOKENS 2048
#define HID 1024
#define ISZ 1408
#define NEXP 8
#define RROWS 5120   // 4096 rows + per-expert 128-alignment padding

typedef __bf16 bf16x8 __attribute__((ext_vector_type(8)));
typedef __bf16 bf16x4 __attribute__((ext_vector_type(4)));
typedef float  f32x4  __attribute__((ext_vector_type(4)));
typedef float  f32x16 __attribute__((ext_vector_type(16)));

__device__ __forceinline__ void gload16(const void* g, void* l) {
    __builtin_amdgcn_global_load_lds(
        (const __attribute__((address_space(1))) void*)g,
        (__attribute__((address_space(3))) void*)l,
        16, 0, 0);
}

// counted-vmcnt barrier: newest N loads may stay in flight; everything older done.
#define PIPE_BARRIER(N)                                              \
    asm volatile("s_waitcnt vmcnt(" #N ") lgkmcnt(0)" ::: "memory"); \
    __builtin_amdgcn_sched_barrier(0);                               \
    __builtin_amdgcn_s_barrier();                                    \
    __builtin_amdgcn_sched_barrier(0);

// ---------------- Router: one wave per token; also converts x -> bf16 xb ----------------
__global__ __launch_bounds__(256) void router_kernel(
    const float* __restrict__ x, const float* __restrict__ gw,
    int* __restrict__ sel, float* __restrict__ wt, int* __restrict__ counts,
    __bf16* __restrict__ xb)
{
    __shared__ float sgw[HID * NEXP];  // 32 KB
    for (int i = threadIdx.x; i < HID * NEXP; i += 256) sgw[i] = gw[i];
    __syncthreads();

    const int wave = threadIdx.x >> 6;
    const int lane = threadIdx.x & 63;
    const int t = blockIdx.x * 4 + wave;
    const float* xr = x + (size_t)t * HID;

    {
        const int c0 = lane * 16;
        float4 v0 = *(const float4*)(xr + c0);
        float4 v1 = *(const float4*)(xr + c0 + 4);
        float4 v2 = *(const float4*)(xr + c0 + 8);
        float4 v3 = *(const float4*)(xr + c0 + 12);
        bf16x8 o0, o1;
        o0[0]=(__bf16)v0.x; o0[1]=(__bf16)v0.y; o0[2]=(__bf16)v0.z; o0[3]=(__bf16)v0.w;
        o0[4]=(__bf16)v1.x; o0[5]=(__bf16)v1.y; o0[6]=(__bf16)v1.z; o0[7]=(__bf16)v1.w;
        o1[0]=(__bf16)v2.x; o1[1]=(__bf16)v2.y; o1[2]=(__bf16)v2.z; o1[3]=(__bf16)v2.w;
        o1[4]=(__bf16)v3.x; o1[5]=(__bf16)v3.y; o1[6]=(__bf16)v3.z; o1[7]=(__bf16)v3.w;
        *(bf16x8*)(xb + (size_t)t * HID + c0) = o0;
        *(bf16x8*)(xb + (size_t)t * HID + c0 + 8) = o1;
    }

    const int e = lane & 7;
    const int c = lane >> 3;
    float acc = 0.f;
    #pragma unroll 4
    for (int h = c * 128; h < c * 128 + 128; ++h)
        acc += xr[h] * sgw[h * NEXP + e];
    acc += __shfl_xor(acc, 8);
    acc += __shfl_xor(acc, 16);
    acc += __shfl_xor(acc, 32);
    float m = acc;
    #pragma unroll
    for (int d = 1; d < 8; d <<= 1) m = fmaxf(m, __shfl_xor(m, d));
    float p = expf(acc - m);
    float s = p;
    #pragma unroll
    for (int d = 1; d < 8; d <<= 1) s += __shfl_xor(s, d);
    p /= s;
    float p1 = p; int e1 = e;
    #pragma unroll
    for (int d = 1; d < 8; d <<= 1) {
        float op = __shfl_xor(p1, d); int oe = __shfl_xor(e1, d);
        if (op > p1 || (op == p1 && oe < e1)) { p1 = op; e1 = oe; }
    }
    float pm = (e == e1) ? -1.0f : p;
    float p2 = pm; int e2 = e;
    #pragma unroll
    for (int d = 1; d < 8; d <<= 1) {
        float op = __shfl_xor(p2, d); int oe = __shfl_xor(e2, d);
        if (op > p2 || (op == p2 && oe < e2)) { p2 = op; e2 = oe; }
    }
    if (lane == 0) {
        float inv = 1.0f / (p1 + p2);
        sel[t * 2 + 0] = e1; sel[t * 2 + 1] = e2;
        wt[t * 2 + 0] = p1 * inv; wt[t * 2 + 1] = p2 * inv;
        atomicAdd(&counts[e1], 1); atomicAdd(&counts[e2], 1);
    }
}

__global__ void scan_kernel(const int* __restrict__ counts, int* __restrict__ offs,
                            int* __restrict__ ncnt, int* __restrict__ cursor)
{
    if (threadIdx.x == 0 && blockIdx.x == 0) {
        int cur = 0;
        for (int e = 0; e < NEXP; ++e) {
            offs[e] = cur;
            int n = (counts[e] + 127) & ~127;   // 128-row tile alignment
            ncnt[e] = n;
            cursor[e] = 0;
            cur += n;
        }
    }
}

__global__ __launch_bounds__(256) void assign_kernel(
    const int* __restrict__ sel, const float* __restrict__ wt,
    const int* __restrict__ offs, int* __restrict__ cursor,
    int* __restrict__ rtok, float* __restrict__ rwt, int* __restrict__ tok2row)
{
    int t = blockIdx.x * 256 + threadIdx.x;
    if (t >= T_TOKENS) return;
    #pragma unroll
    for (int k = 0; k < 2; ++k) {
        int e = sel[t * 2 + k];
        int pos = atomicAdd(&cursor[e], 1);
        int row = offs[e] + pos;
        rtok[row] = t;
        rwt[row] = wt[t * 2 + k];
        tok2row[t * 2 + k] = row;
    }
}

// ---------------- Fused transpose+convert for all 3 weights ----------------
__global__ __launch_bounds__(256) void tcvt_all_kernel(
    const float* __restrict__ wg, const float* __restrict__ wu, const float* __restrict__ wd,
    __bf16* __restrict__ wgT, __bf16* __restrict__ wuT, __bf16* __restrict__ wdT)
{
    const int z = blockIdx.z;
    const int e = z & 7;
    const float* in;
    __bf16* out;
    int R, C, r0, c0;
    if (z < 16) {
        R = HID; C = ISZ;
        r0 = blockIdx.y * 64; c0 = blockIdx.x * 64;
        in  = (z < 8 ? wg : wu)  + (size_t)e * R * C;
        out = (z < 8 ? wgT : wuT) + (size_t)e * R * C;
    } else {
        R = ISZ; C = HID;
        r0 = blockIdx.x * 64; c0 = blockIdx.y * 64;
        in  = wd  + (size_t)e * R * C;
        out = wdT + (size_t)e * R * C;
    }
    __shared__ float t[64][65];
    const int tid = threadIdx.x;
    const int lr  = tid >> 4;
    const int lc4 = (tid & 15) * 4;
    #pragma unroll
    for (int p = 0; p < 4; ++p) {
        float4 v = *(const float4*)(in + (size_t)(r0 + p * 16 + lr) * C + c0 + lc4);
        t[p * 16 + lr][lc4 + 0] = v.x;
        t[p * 16 + lr][lc4 + 1] = v.y;
        t[p * 16 + lr][lc4 + 2] = v.z;
        t[p * 16 + lr][lc4 + 3] = v.w;
    }
    __syncthreads();
    #pragma unroll
    for (int p = 0; p < 4; ++p) {
        int oc = p * 16 + lr;
        bf16x4 w;
        #pragma unroll
        for (int j = 0; j < 4; ++j) w[j] = (__bf16)t[lc4 + j][oc];
        *(bf16x4*)(out + (size_t)(c0 + oc) * R + r0 + lc4) = w;
    }
}

// ---------------- FFN1: inter = silu(x@WgT') * (x@WuT') ----------------
// BM=128, BN=64(G)+64(U), BK=32, 32x32x16 MFMA, 4 waves (wr,wc).
// 3-buf depth-2 counted-vmcnt pipeline (4 loads/stage), 4-chunk XOR swizzle,
// A staged from token-space xb via per-lane rtok indirection.
__global__ __launch_bounds__(256) void ffn1_kernel(
    const __bf16* __restrict__ xb, const int* __restrict__ rtok,
    const __bf16* __restrict__ wgT, const __bf16* __restrict__ wuT,
    const int* __restrict__ offs, const int* __restrict__ ncnt,
    __bf16* __restrict__ inter)
{
    // grid 5632 = 22 stripes x 8 e x 32 rt; XCD chunks of 704
    const int n  = blockIdx.x;
    const int nn = (n & 7) * 704 + (n >> 3);
    const int i0 = (nn >> 8) * 64;
    const int rem = nn & 255;
    const int e  = rem >> 5;
    const int rt = rem & 31;
    if (rt * 128 >= ncnt[e]) return;
    const int rowbase = offs[e] + rt * 128;

    __shared__ __align__(16) __bf16 sA[3][128][32];  // 24 KB
    __shared__ __align__(16) __bf16 sG[3][64][32];   // 12 KB
    __shared__ __align__(16) __bf16 sU[3][64][32];   // 12 KB -> 48 KB, 3 blocks/CU

    const int tid  = threadIdx.x;
    const int lane = tid & 63;
    const int wid  = tid >> 6;
    const int wr = wid >> 1, wc = wid & 1;
    const int l31 = lane & 31;
    const int kg  = lane >> 5;          // k-half 0/1

    // staging lanes: 16 rows per gload16: row = lane>>2, slot chunk = lane&3
    // slot c holds global chunk c ^ (row&3)  (involution within 4-row stripe)
    const int r16 = lane >> 2;                       // 0..15
    const int cz  = (((lane & 3) ^ (r16 & 3)) * 8);  // source element offset
    const __bf16* Aj[2];
    #pragma unroll
    for (int j = 0; j < 2; ++j) {
        int row = rowbase + wid * 32 + 16 * j + r16;
        int tok = rtok[row];
        int src = (tok < 0) ? T_TOKENS : tok;        // pad rows -> zero row
        Aj[j] = xb + (size_t)src * HID + cz;
    }
    const size_t wbase = (size_t)e * ISZ * HID + (size_t)(i0 + wid * 16 + r16) * HID + cz;
    const __bf16* G0 = wgT + wbase;
    const __bf16* U0 = wuT + wbase;

    f32x16 accG[2], accU[2];
    #pragma unroll
    for (int m = 0; m < 2; ++m) {
        #pragma unroll
        for (int r = 0; r < 16; ++r) { accG[m][r] = 0.f; accU[m][r] = 0.f; }
    }

    auto stage = [&](int b, int k0) {   // 4 gload16 per wave
        gload16(Aj[0] + k0, &sA[b][wid * 32][0]);
        gload16(Aj[1] + k0, &sA[b][wid * 32 + 16][0]);
        gload16(G0 + k0, &sG[b][wid * 16][0]);
        gload16(U0 + k0, &sU[b][wid * 16][0]);
    };
    auto compute = [&](int b) {
        #pragma unroll
        for (int s = 0; s < 2; ++s) {
            const int ch = ((2 * s + kg) ^ (l31 & 3)) * 8;
            bf16x8 a0 = *(const bf16x8*)&sA[b][wr * 64 + l31][ch];
            bf16x8 a1 = *(const bf16x8*)&sA[b][wr * 64 + 32 + l31][ch];
            bf16x8 g_ = *(const bf16x8*)&sG[b][wc * 32 + l31][ch];
            bf16x8 u_ = *(const bf16x8*)&sU[b][wc * 32 + l31][ch];
            __builtin_amdgcn_s_setprio(1);
            accG[0] = __builtin_amdgcn_mfma_f32_32x32x16_bf16(a0, g_, accG[0], 0, 0, 0);
            accG[1] = __builtin_amdgcn_mfma_f32_32x32x16_bf16(a1, g_, accG[1], 0, 0, 0);
            accU[0] = __builtin_amdgcn_mfma_f32_32x32x16_bf16(a0, u_, accU[0], 0, 0, 0);
            accU[1] = __builtin_amdgcn_mfma_f32_32x32x16_bf16(a1, u_, accU[1], 0, 0, 0);
            __builtin_amdgcn_s_setprio(0);
        }
    };

    const int nIter = HID / 32;   // 32
    stage(0, 0);
    stage(1, 32);
    PIPE_BARRIER(4)               // stage0 done -> buf0 ready; stage1 (4 loads) in flight
    for (int i = 0; i < nIter; ++i) {
        int ks = (i + 2 < nIter) ? (i + 2) * 32 : 0;   // clamped dead stage keeps counts uniform
        stage((i + 2) % 3, ks);
        compute(i % 3);
        PIPE_BARRIER(4)           // newest stage in flight; buf i+1 landed; ds_reads drained
    }

    // epilogue: silu(G)*U -> bf16 inter (D: col = lane&31, row = (r&3)+8*(r>>2)+4*kg)
    #pragma unroll
    for (int m = 0; m < 2; ++m) {
        const int base_row = rowbase + wr * 64 + m * 32;
        #pragma unroll
        for (int r = 0; r < 16; ++r) {
            float g = accG[m][r];
            float u = accU[m][r];
            float v = g / (1.0f + __expf(-g)) * u;
            int row = base_row + (r & 3) + 8 * (r >> 2) + 4 * kg;
            inter[(size_t)row * ISZ + i0 + wc * 32 + l31] = (__bf16)v;
        }
    }
}

// ---------------- FFN2: y[row] = rwt[row] * (inter[row] @ WdT')  (no atomics) ----------------
// BM=128, BN=64, BK=32, 32x32x16 MFMA, 4 waves (wr,wc): wave owns 64 rows x 32 cols.
// 3-buf depth-2 counted-vmcnt pipeline (3 loads/stage), same swizzle.
__global__ __launch_bounds__(256) void ffn2_kernel(
    const __bf16* __restrict__ inter, const __bf16* __restrict__ wdT,
    const float* __restrict__ rwt,
    const int* __restrict__ offs, const int* __restrict__ ncnt,
    float* __restrict__ y)
{
    // grid 4096 = 16 stripes x 8 e x 32 rt; XCD chunks of 512
    const int n  = blockIdx.x;
    const int nn = (n & 7) * 512 + (n >> 3);
    const int n0 = (nn >> 8) * 64;          // stripe 0..15
    const int rem = nn & 255;
    const int e  = rem >> 5;
    const int rt = rem & 31;
    if (rt * 128 >= ncnt[e]) return;
    const int rowbase = offs[e] + rt * 128;

    __shared__ __align__(16) __bf16 sA[3][128][32];  // 24 KB
    __shared__ __align__(16) __bf16 sB[3][64][32];   // 12 KB -> 36 KB

    const int tid  = threadIdx.x;
    const int lane = tid & 63;
    const int wid  = tid >> 6;
    const int wr = wid >> 1, wc = wid & 1;
    const int l31 = lane & 31;
    const int kg  = lane >> 5;

    const int r16 = lane >> 2;
    const int cz  = (((lane & 3) ^ (r16 & 3)) * 8);
    const __bf16* A0 = inter + (size_t)(rowbase + wid * 32 + r16) * ISZ + cz;
    const __bf16* B0 = wdT + (size_t)e * HID * ISZ + (size_t)(n0 + wid * 16 + r16) * ISZ + cz;
    const size_t rstepA = (size_t)16 * ISZ;

    f32x16 acc[2];
    #pragma unroll
    for (int m = 0; m < 2; ++m)
        #pragma unroll
        for (int r = 0; r < 16; ++r) acc[m][r] = 0.f;

    auto stage = [&](int b, int k0) {   // 3 gload16 per wave
        gload16(A0 + k0,          &sA[b][wid * 32][0]);
        gload16(A0 + k0 + rstepA, &sA[b][wid * 32 + 16][0]);
        gload16(B0 + k0,          &sB[b][wid * 16][0]);
    };
    auto compute = [&](int b) {
        #pragma unroll
        for (int s = 0; s < 2; ++s) {
            const int ch = ((2 * s + kg) ^ (l31 & 3)) * 8;
            bf16x8 a0 = *(const bf16x8*)&sA[b][wr * 64 + l31][ch];
            bf16x8 a1 = *(const bf16x8*)&sA[b][wr * 64 + 32 + l31][ch];
            bf16x8 b_ = *(const bf16x8*)&sB[b][wc * 32 + l31][ch];
            __builtin_amdgcn_s_setprio(1);
            acc[0] = __builtin_amdgcn_mfma_f32_32x32x16_bf16(a0, b_, acc[0], 0, 0, 0);
            acc[1] = __builtin_amdgcn_mfma_f32_32x32x16_bf16(a1, b_, acc[1], 0, 0, 0);
            __builtin_amdgcn_s_setprio(0);
        }
    };

    const int nIter = ISZ / 32;   // 44
    stage(0, 0);
    stage(1, 32);
    PIPE_BARRIER(3)
    for (int i = 0; i < nIter; ++i) {
        int ks = (i + 2 < nIter) ? (i + 2) * 32 : 0;
        stage((i + 2) % 3, ks);
        compute(i % 3);
        PIPE_BARRIER(3)
    }

    #pragma unroll
    for (int m = 0; m < 2; ++m) {
        const int base_row = rowbase + wr * 64 + m * 32;
        const int col = n0 + wc * 32 + l31;
        #pragma unroll
        for (int r = 0; r < 16; ++r) {
            int row = base_row + (r & 3) + 8 * (r >> 2) + 4 * kg;
            y[(size_t)row * HID + col] = rwt[row] * acc[m][r];
        }
    }
}

// ---------------- Combine: out[t] = y[row0(t)] + y[row1(t)] ----------------
__global__ __launch_bounds__(256) void combine_kernel(
    const float* __restrict__ y, const int* __restrict__ tok2row, float* __restrict__ out)
{
    const int idx = blockIdx.x * 256 + threadIdx.x;
    const int t = idx >> 8;
    const int c = (idx & 255) * 4;
    const int r0 = tok2row[t * 2];
    const int r1 = tok2row[t * 2 + 1];
    float4 a = *(const float4*)(y + (size_t)r0 * HID + c);
    float4 b = *(const float4*)(y + (size_t)r1 * HID + c);
    float4 o = {a.x + b.x, a.y + b.y, a.z + b.z, a.w + b.w};
    *(float4*)(out + (size_t)t * HID + c) = o;
}

extern "C" void kernel_launch(void* const* d_in, const int* in_sizes, int n_in,
                              void* d_out, int out_size, void* d_ws, size_t ws_size,
                              hipStream_t stream) {
    const float* x  = (const float*)d_in[0];
    const float* gw = (const float*)d_in[1];
    const float* wg = (const float*)d_in[2];
    const float* wu = (const float*)d_in[3];
    const float* wd = (const float*)d_in[4];
    float* out = (float*)d_out;

    char* ws = (char*)d_ws;
    int*    counts  = (int*)(ws + 0);
    int*    cursor  = (int*)(ws + 32);
    int*    offs    = (int*)(ws + 64);
    int*    ncnt    = (int*)(ws + 96);
    int*    sel     = (int*)(ws + 128);
    float*  wtp     = (float*)(ws + 16512);
    int*    rtok    = (int*)(ws + 32896);
    float*  rwt     = (float*)(ws + 53376);
    int*    tok2row = (int*)(ws + 73856);
    __bf16* xb      = (__bf16*)(ws + 90240);            // (2048+1)*1024 bf16 = 4.2 MB
    __bf16* inter   = (__bf16*)(ws + 10576000);         // 14.42 MB
    __bf16* wgT     = (__bf16*)(ws + 24993920);         // 23.07 MB
    __bf16* wuT     = (__bf16*)(ws + 48062592);         // 23.07 MB
    __bf16* wdT     = (__bf16*)(ws + 71131264);         // 23.07 MB
    float*  y       = (float*)wgT;                      // alias: wgT dead after ffn1

    hipMemsetAsync(counts, 0, 32, stream);
    hipMemsetAsync(rtok, 0xFF, RROWS * 4, stream);
    hipMemsetAsync(xb + (size_t)T_TOKENS * HID, 0, HID * sizeof(__bf16), stream);  // zero row

    tcvt_all_kernel<<<dim3(ISZ / 64, HID / 64, 24), 256, 0, stream>>>(wg, wu, wd, wgT, wuT, wdT);

    router_kernel<<<T_TOKENS / 4, 256, 0, stream>>>(x, gw, sel, wtp, counts, xb);
    scan_kernel<<<1, 64, 0, stream>>>(counts, offs, ncnt, cursor);
    assign_kernel<<<(T_TOKENS + 255) / 256, 256, 0, stream>>>(sel, wtp, offs, cursor, rtok, rwt, tok2row);

    ffn1_kernel<<<22 * 256, 256, 0, stream>>>(xb, rtok, wgT, wuT, offs, ncnt, inter);  // 5632
    ffn2_kernel<<<16 * 256, 256, 0, stream>>>(inter, wdT, rwt, offs, ncnt, y);         // 4096
    combine_kernel<<<(T_TOKENS * HID / 4) / 256, 256, 0, stream>>>(y, tok2row, out);
}

// Round 12
// 215.110 us; speedup vs baseline: 1.1340x; 1.1340x over previous
//
#include <hip/hip_runtime.h>
#include <hip/hip_bf16.h>

#define T_TOKENS 2048
#define HID 1024
#define ISZ 1408
#define NEXP 8
#define RROWS 5120   // 4096 rows + per-expert 128-alignment padding

typedef __bf16 bf16x8 __attribute__((ext_vector_type(8)));
typedef __bf16 bf16x4 __attribute__((ext_vector_type(4)));
typedef float  f32x16 __attribute__((ext_vector_type(16)));

__device__ __forceinline__ void gload16(const void* g, void* l) {
    __builtin_amdgcn_global_load_lds(
        (const __attribute__((address_space(1))) void*)g,
        (__attribute__((address_space(3))) void*)l,
        16, 0, 0);
}

// counted-vmcnt barrier: newest N loads may stay in flight; everything older done.
#define PIPE_BARRIER(N)                                              \
    asm volatile("s_waitcnt vmcnt(" #N ") lgkmcnt(0)" ::: "memory"); \
    __builtin_amdgcn_sched_barrier(0);                               \
    __builtin_amdgcn_s_barrier();                                    \
    __builtin_amdgcn_sched_barrier(0);

// ---------------- Router: one wave per token; also converts x -> bf16 xb ----------------
__global__ __launch_bounds__(256) void router_kernel(
    const float* __restrict__ x, const float* __restrict__ gw,
    int* __restrict__ sel, float* __restrict__ wt, int* __restrict__ counts,
    __bf16* __restrict__ xb)
{
    __shared__ float sgw[HID * NEXP];  // 32 KB
    for (int i = threadIdx.x; i < HID * NEXP; i += 256) sgw[i] = gw[i];
    __syncthreads();

    const int wave = threadIdx.x >> 6;
    const int lane = threadIdx.x & 63;
    const int t = blockIdx.x * 4 + wave;
    const float* xr = x + (size_t)t * HID;

    {
        const int c0 = lane * 16;
        float4 v0 = *(const float4*)(xr + c0);
        float4 v1 = *(const float4*)(xr + c0 + 4);
        float4 v2 = *(const float4*)(xr + c0 + 8);
        float4 v3 = *(const float4*)(xr + c0 + 12);
        bf16x8 o0, o1;
        o0[0]=(__bf16)v0.x; o0[1]=(__bf16)v0.y; o0[2]=(__bf16)v0.z; o0[3]=(__bf16)v0.w;
        o0[4]=(__bf16)v1.x; o0[5]=(__bf16)v1.y; o0[6]=(__bf16)v1.z; o0[7]=(__bf16)v1.w;
        o1[0]=(__bf16)v2.x; o1[1]=(__bf16)v2.y; o1[2]=(__bf16)v2.z; o1[3]=(__bf16)v2.w;
        o1[4]=(__bf16)v3.x; o1[5]=(__bf16)v3.y; o1[6]=(__bf16)v3.z; o1[7]=(__bf16)v3.w;
        *(bf16x8*)(xb + (size_t)t * HID + c0) = o0;
        *(bf16x8*)(xb + (size_t)t * HID + c0 + 8) = o1;
    }

    const int e = lane & 7;
    const int c = lane >> 3;
    float acc = 0.f;
    #pragma unroll 4
    for (int h = c * 128; h < c * 128 + 128; ++h)
        acc += xr[h] * sgw[h * NEXP + e];
    acc += __shfl_xor(acc, 8);
    acc += __shfl_xor(acc, 16);
    acc += __shfl_xor(acc, 32);
    float m = acc;
    #pragma unroll
    for (int d = 1; d < 8; d <<= 1) m = fmaxf(m, __shfl_xor(m, d));
    float p = expf(acc - m);
    float s = p;
    #pragma unroll
    for (int d = 1; d < 8; d <<= 1) s += __shfl_xor(s, d);
    p /= s;
    float p1 = p; int e1 = e;
    #pragma unroll
    for (int d = 1; d < 8; d <<= 1) {
        float op = __shfl_xor(p1, d); int oe = __shfl_xor(e1, d);
        if (op > p1 || (op == p1 && oe < e1)) { p1 = op; e1 = oe; }
    }
    float pm = (e == e1) ? -1.0f : p;
    float p2 = pm; int e2 = e;
    #pragma unroll
    for (int d = 1; d < 8; d <<= 1) {
        float op = __shfl_xor(p2, d); int oe = __shfl_xor(e2, d);
        if (op > p2 || (op == p2 && oe < e2)) { p2 = op; e2 = oe; }
    }
    if (lane == 0) {
        float inv = 1.0f / (p1 + p2);
        sel[t * 2 + 0] = e1; sel[t * 2 + 1] = e2;
        wt[t * 2 + 0] = p1 * inv; wt[t * 2 + 1] = p2 * inv;
        atomicAdd(&counts[e1], 1); atomicAdd(&counts[e2], 1);
    }
}

// ---------------- Scan + assign fused (single block) ----------------
__global__ __launch_bounds__(256) void scan_assign_kernel(
    const int* __restrict__ counts, int* __restrict__ offs, int* __restrict__ ncnt,
    const int* __restrict__ sel, const float* __restrict__ wt,
    int* __restrict__ rtok, float* __restrict__ rwt, int* __restrict__ tok2row)
{
    __shared__ int soff[NEXP];
    __shared__ int scur[NEXP];
    if (threadIdx.x == 0) {
        int cur = 0;
        for (int e = 0; e < NEXP; ++e) {
            soff[e] = cur; offs[e] = cur;
            int n = (counts[e] + 127) & ~127;   // 128-row tile alignment
            ncnt[e] = n; scur[e] = 0;
            cur += n;
        }
    }
    __syncthreads();
    for (int t = threadIdx.x; t < T_TOKENS; t += 256) {
        #pragma unroll
        for (int k = 0; k < 2; ++k) {
            int e = sel[t * 2 + k];
            int pos = atomicAdd(&scur[e], 1);
            int row = soff[e] + pos;
            rtok[row] = t;
            rwt[row] = wt[t * 2 + k];
            tok2row[t * 2 + k] = row;
        }
    }
}

// ---------------- Fused transpose+convert for all 3 weights ----------------
__global__ __launch_bounds__(256) void tcvt_all_kernel(
    const float* __restrict__ wg, const float* __restrict__ wu, const float* __restrict__ wd,
    __bf16* __restrict__ wgT, __bf16* __restrict__ wuT, __bf16* __restrict__ wdT)
{
    const int z = blockIdx.z;
    const int e = z & 7;
    const float* in;
    __bf16* out;
    int R, C, r0, c0;
    if (z < 16) {
        R = HID; C = ISZ;
        r0 = blockIdx.y * 64; c0 = blockIdx.x * 64;
        in  = (z < 8 ? wg : wu)  + (size_t)e * R * C;
        out = (z < 8 ? wgT : wuT) + (size_t)e * R * C;
    } else {
        R = ISZ; C = HID;
        r0 = blockIdx.x * 64; c0 = blockIdx.y * 64;
        in  = wd  + (size_t)e * R * C;
        out = wdT + (size_t)e * R * C;
    }
    __shared__ float t[64][65];
    const int tid = threadIdx.x;
    const int lr  = tid >> 4;
    const int lc4 = (tid & 15) * 4;
    #pragma unroll
    for (int p = 0; p < 4; ++p) {
        float4 v = *(const float4*)(in + (size_t)(r0 + p * 16 + lr) * C + c0 + lc4);
        t[p * 16 + lr][lc4 + 0] = v.x;
        t[p * 16 + lr][lc4 + 1] = v.y;
        t[p * 16 + lr][lc4 + 2] = v.z;
        t[p * 16 + lr][lc4 + 3] = v.w;
    }
    __syncthreads();
    #pragma unroll
    for (int p = 0; p < 4; ++p) {
        int oc = p * 16 + lr;
        bf16x4 w;
        #pragma unroll
        for (int j = 0; j < 4; ++j) w[j] = (__bf16)t[lc4 + j][oc];
        *(bf16x4*)(out + (size_t)(c0 + oc) * R + r0 + lc4) = w;
    }
}

// ---------------- FFN1: inter = silu(x@WgT') * (x@WuT') ----------------
// BM=128, BN=64(G)+64(U), BK=64 split in 2 halves of 32. 32x32x16 MFMA.
// 2-dbuf x 2-half LDS; per phase: stage one half (4 gloads) + compute one half;
// vmcnt(8) at each barrier (2 halves always in flight) -- never drains.
// Half-rows are 64B: swizzle slot = chunk ^ ((row>>1)&3)  (quarter-wave conflict-free).
__global__ __launch_bounds__(256) void ffn1_kernel(
    const __bf16* __restrict__ xb, const int* __restrict__ rtok,
    const __bf16* __restrict__ wgT, const __bf16* __restrict__ wuT,
    const int* __restrict__ offs, const int* __restrict__ ncnt,
    __bf16* __restrict__ inter)
{
    // grid 5632 = 22 stripes x 8 e x 32 rt; XCD chunks of 704
    const int n  = blockIdx.x;
    const int nn = (n & 7) * 704 + (n >> 3);
    const int i0 = (nn >> 8) * 64;
    const int rem = nn & 255;
    const int e  = rem >> 5;
    const int rt = rem & 31;
    if (rt * 128 >= ncnt[e]) return;
    const int rowbase = offs[e] + rt * 128;

    __shared__ __align__(16) __bf16 sA[2][2][128][32];  // 32 KB
    __shared__ __align__(16) __bf16 sG[2][2][64][32];   // 16 KB
    __shared__ __align__(16) __bf16 sU[2][2][64][32];   // 16 KB -> 64 KB total

    const int tid  = threadIdx.x;
    const int lane = tid & 63;
    const int wid  = tid >> 6;
    const int wr = wid >> 1, wc = wid & 1;
    const int l31 = lane & 31;
    const int kg  = lane >> 5;          // k-half-of-16 0/1

    // staging: 16 rows per gload16 (64B rows); lane: row = lane>>2, slot = lane&3
    // slot holds global chunk (lane&3)^((r16>>1)&3)  (involution)
    const int r16 = lane >> 2;
    const int cz  = (((lane & 3) ^ ((r16 >> 1) & 3)) * 8);   // swizzled source elem offset
    const __bf16* Aj[2];
    #pragma unroll
    for (int j = 0; j < 2; ++j) {
        int row = rowbase + wid * 32 + 16 * j + r16;
        int tok = rtok[row];
        int src = (tok < 0) ? T_TOKENS : tok;        // pad rows -> zero row
        Aj[j] = xb + (size_t)src * HID + cz;
    }
    const size_t wbase = (size_t)e * ISZ * HID + (size_t)(i0 + wid * 16 + r16) * HID + cz;
    const __bf16* G0 = wgT + wbase;
    const __bf16* U0 = wuT + wbase;

    f32x16 accG[2], accU[2];
    #pragma unroll
    for (int m = 0; m < 2; ++m) {
        #pragma unroll
        for (int r = 0; r < 16; ++r) { accG[m][r] = 0.f; accU[m][r] = 0.f; }
    }

    auto stageH = [&](int d, int h, int kbase) {   // 4 gload16 per wave
        const int k0 = kbase + h * 32;
        gload16(Aj[0] + k0, &sA[d][h][wid * 32][0]);
        gload16(Aj[1] + k0, &sA[d][h][wid * 32 + 16][0]);
        gload16(G0 + k0, &sG[d][h][wid * 16][0]);
        gload16(U0 + k0, &sU[d][h][wid * 16][0]);
    };
    auto computeH = [&](int d, int h) {
        #pragma unroll
        for (int s = 0; s < 2; ++s) {
            const int c = 2 * s + kg;
            const int ra = wr * 64 + l31;            // (ra>>1)&3 == (l31>>1)&3
            const int rb = wc * 32 + l31;
            const int sw = ((l31 >> 1) & 3);
            bf16x8 a0 = *(const bf16x8*)&sA[d][h][ra][((c ^ sw)) * 8];
            bf16x8 a1 = *(const bf16x8*)&sA[d][h][ra + 32][((c ^ sw)) * 8];
            bf16x8 g_ = *(const bf16x8*)&sG[d][h][rb][((c ^ sw)) * 8];
            bf16x8 u_ = *(const bf16x8*)&sU[d][h][rb][((c ^ sw)) * 8];
            __builtin_amdgcn_s_setprio(1);
            accG[0] = __builtin_amdgcn_mfma_f32_32x32x16_bf16(a0, g_, accG[0], 0, 0, 0);
            accG[1] = __builtin_amdgcn_mfma_f32_32x32x16_bf16(a1, g_, accG[1], 0, 0, 0);
            accU[0] = __builtin_amdgcn_mfma_f32_32x32x16_bf16(a0, u_, accU[0], 0, 0, 0);
            accU[1] = __builtin_amdgcn_mfma_f32_32x32x16_bf16(a1, u_, accU[1], 0, 0, 0);
            __builtin_amdgcn_s_setprio(0);
        }
    };

    const int nT = HID / 64;   // 16 K-tiles
    stageH(0, 0, 0);           // t0 h0
    stageH(0, 1, 0);           // t0 h1
    stageH(1, 0, 64);          // t1 h0   -> 12 outstanding
    PIPE_BARRIER(8)            // t0h0 landed
    for (int t = 0; t < nT; ++t) {
        const int d = t & 1;
        // phase A: stage (t+1, h1) into buf d^1; compute half 0
        { int kb = (t + 1 < nT) ? (t + 1) * 64 : 0; stageH(d ^ 1, 1, kb); }
        computeH(d, 0);
        PIPE_BARRIER(8)        // t_i h1 landed (needed by phase B)
        // phase B: stage (t+2, h0) into buf d; compute half 1
        { int kb = (t + 2 < nT) ? (t + 2) * 64 : 0; stageH(d, 0, kb); }
        computeH(d, 1);
        PIPE_BARRIER(8)        // t_{i+1} h0 landed (needed by next phase A)
    }

    // epilogue: silu(G)*U -> bf16 inter (D: col = lane&31, row = (r&3)+8*(r>>2)+4*kg)
    #pragma unroll
    for (int m = 0; m < 2; ++m) {
        const int base_row = rowbase + wr * 64 + m * 32;
        #pragma unroll
        for (int r = 0; r < 16; ++r) {
            float g = accG[m][r];
            float u = accU[m][r];
            float v = g / (1.0f + __expf(-g)) * u;
            int row = base_row + (r & 3) + 8 * (r >> 2) + 4 * kg;
            inter[(size_t)row * ISZ + i0 + wc * 32 + l31] = (__bf16)v;
        }
    }
}

// ---------------- FFN2: y[row] = rwt[row] * (inter[row] @ WdT')  (no atomics) ----------------
// BM=128, BN=64, BK=64 in 2 halves. Same phase pipeline, vmcnt(6). 48 KB -> 3 blocks/CU.
__global__ __launch_bounds__(256) void ffn2_kernel(
    const __bf16* __restrict__ inter, const __bf16* __restrict__ wdT,
    const float* __restrict__ rwt,
    const int* __restrict__ offs, const int* __restrict__ ncnt,
    float* __restrict__ y)
{
    // grid 4096 = 16 stripes x 8 e x 32 rt; XCD chunks of 512
    const int n  = blockIdx.x;
    const int nn = (n & 7) * 512 + (n >> 3);
    const int n0 = (nn >> 8) * 64;
    const int rem = nn & 255;
    const int e  = rem >> 5;
    const int rt = rem & 31;
    if (rt * 128 >= ncnt[e]) return;
    const int rowbase = offs[e] + rt * 128;

    __shared__ __align__(16) __bf16 sA[2][2][128][32];  // 32 KB
    __shared__ __align__(16) __bf16 sB[2][2][64][32];   // 16 KB -> 48 KB

    const int tid  = threadIdx.x;
    const int lane = tid & 63;
    const int wid  = tid >> 6;
    const int wr = wid >> 1, wc = wid & 1;
    const int l31 = lane & 31;
    const int kg  = lane >> 5;

    const int r16 = lane >> 2;
    const int cz  = (((lane & 3) ^ ((r16 >> 1) & 3)) * 8);
    const __bf16* A0 = inter + (size_t)(rowbase + wid * 32 + r16) * ISZ + cz;
    const size_t rstepA = (size_t)16 * ISZ;
    const __bf16* B0 = wdT + (size_t)e * HID * ISZ + (size_t)(n0 + wid * 16 + r16) * ISZ + cz;

    f32x16 acc[2];
    #pragma unroll
    for (int m = 0; m < 2; ++m)
        #pragma unroll
        for (int r = 0; r < 16; ++r) acc[m][r] = 0.f;

    auto stageH = [&](int d, int h, int kbase) {   // 3 gload16 per wave
        const int k0 = kbase + h * 32;
        gload16(A0 + k0,          &sA[d][h][wid * 32][0]);
        gload16(A0 + k0 + rstepA, &sA[d][h][wid * 32 + 16][0]);
        gload16(B0 + k0,          &sB[d][h][wid * 16][0]);
    };
    auto computeH = [&](int d, int h) {
        #pragma unroll
        for (int s = 0; s < 2; ++s) {
            const int c = 2 * s + kg;
            const int ra = wr * 64 + l31;
            const int rb = wc * 32 + l31;
            const int sw = ((l31 >> 1) & 3);
            bf16x8 a0 = *(const bf16x8*)&sA[d][h][ra][((c ^ sw)) * 8];
            bf16x8 a1 = *(const bf16x8*)&sA[d][h][ra + 32][((c ^ sw)) * 8];
            bf16x8 b_ = *(const bf16x8*)&sB[d][h][rb][((c ^ sw)) * 8];
            __builtin_amdgcn_s_setprio(1);
            acc[0] = __builtin_amdgcn_mfma_f32_32x32x16_bf16(a0, b_, acc[0], 0, 0, 0);
            acc[1] = __builtin_amdgcn_mfma_f32_32x32x16_bf16(a1, b_, acc[1], 0, 0, 0);
            __builtin_amdgcn_s_setprio(0);
        }
    };

    const int nT = ISZ / 64;   // 22
    stageH(0, 0, 0);
    stageH(0, 1, 0);
    stageH(1, 0, 64);          // 9 outstanding
    PIPE_BARRIER(6)            // t0h0 landed
    for (int t = 0; t < nT; ++t) {
        const int d = t & 1;
        { int kb = (t + 1 < nT) ? (t + 1) * 64 : 0; stageH(d ^ 1, 1, kb); }
        computeH(d, 0);
        PIPE_BARRIER(6)
        { int kb = (t + 2 < nT) ? (t + 2) * 64 : 0; stageH(d, 0, kb); }
        computeH(d, 1);
        PIPE_BARRIER(6)
    }

    #pragma unroll
    for (int m = 0; m < 2; ++m) {
        const int base_row = rowbase + wr * 64 + m * 32;
        const int col = n0 + wc * 32 + l31;
        #pragma unroll
        for (int r = 0; r < 16; ++r) {
            int row = base_row + (r & 3) + 8 * (r >> 2) + 4 * kg;
            y[(size_t)row * HID + col] = rwt[row] * acc[m][r];
        }
    }
}

// ---------------- Combine: out[t] = y[row0(t)] + y[row1(t)] ----------------
__global__ __launch_bounds__(256) void combine_kernel(
    const float* __restrict__ y, const int* __restrict__ tok2row, float* __restrict__ out)
{
    const int idx = blockIdx.x * 256 + threadIdx.x;
    const int t = idx >> 8;
    const int c = (idx & 255) * 4;
    const int r0 = tok2row[t * 2];
    const int r1 = tok2row[t * 2 + 1];
    float4 a = *(const float4*)(y + (size_t)r0 * HID + c);
    float4 b = *(const float4*)(y + (size_t)r1 * HID + c);
    float4 o = {a.x + b.x, a.y + b.y, a.z + b.z, a.w + b.w};
    *(float4*)(out + (size_t)t * HID + c) = o;
}

extern "C" void kernel_launch(void* const* d_in, const int* in_sizes, int n_in,
                              void* d_out, int out_size, void* d_ws, size_t ws_size,
                              hipStream_t stream) {
    const float* x  = (const float*)d_in[0];
    const float* gw = (const float*)d_in[1];
    const float* wg = (const float*)d_in[2];
    const float* wu = (const float*)d_in[3];
    const float* wd = (const float*)d_in[4];
    float* out = (float*)d_out;

    char* ws = (char*)d_ws;
    int*    counts  = (int*)(ws + 0);
    int*    cursor  = (int*)(ws + 32);   // unused (kept for layout stability)
    int*    offs    = (int*)(ws + 64);
    int*    ncnt    = (int*)(ws + 96);
    int*    sel     = (int*)(ws + 128);
    float*  wtp     = (float*)(ws + 16512);
    int*    rtok    = (int*)(ws + 32896);
    float*  rwt     = (float*)(ws + 53376);
    int*    tok2row = (int*)(ws + 73856);
    __bf16* xb      = (__bf16*)(ws + 90240);            // (2048+1)*1024 bf16 = 4.2 MB
    __bf16* inter   = (__bf16*)(ws + 10576000);         // 14.42 MB
    __bf16* wgT     = (__bf16*)(ws + 24993920);         // 23.07 MB
    __bf16* wuT     = (__bf16*)(ws + 48062592);         // 23.07 MB
    __bf16* wdT     = (__bf16*)(ws + 71131264);         // 23.07 MB
    float*  y       = (float*)wgT;                      // alias: wgT dead after ffn1
    (void)cursor;

    hipMemsetAsync(counts, 0, 32, stream);
    hipMemsetAsync(rtok, 0xFF, RROWS * 4, stream);
    hipMemsetAsync(xb + (size_t)T_TOKENS * HID, 0, HID * sizeof(__bf16), stream);  // zero row

    tcvt_all_kernel<<<dim3(ISZ / 64, HID / 64, 24), 256, 0, stream>>>(wg, wu, wd, wgT, wuT, wdT);

    router_kernel<<<T_TOKENS / 4, 256, 0, stream>>>(x, gw, sel, wtp, counts, xb);
    scan_assign_kernel<<<1, 256, 0, stream>>>(counts, offs, ncnt, sel, wtp, rtok, rwt, tok2row);

    ffn1_kernel<<<22 * 256, 256, 0, stream>>>(xb, rtok, wgT, wuT, offs, ncnt, inter);  // 5632
    ffn2_kernel<<<16 * 256, 256, 0, stream>>>(inter, wdT, rwt, offs, ncnt, y);         // 4096
    combine_kernel<<<(T_TOKENS * HID / 4) / 256, 256, 0, stream>>>(y, tok2row, out);
}

// Round 13
// 200.555 us; speedup vs baseline: 1.2163x; 1.0726x over previous
//
#include <hip/hip_runtime.h>
#include <hip/hip_bf16.h>

#define T_TOKENS 2048
#define HID 1024
#define ISZ 1408
#define NEXP 8
#define RMAXROWS 4608   // sum of 64-aligned expert counts <= 4096 + 8*63
#define TILES_MAX 72    // sum ceil(cnt_e/64) <= 4096/64 + 8 = 72

typedef __bf16 bf16x8 __attribute__((ext_vector_type(8)));
typedef __bf16 bf16x4 __attribute__((ext_vector_type(4)));
typedef float  f32x16 __attribute__((ext_vector_type(16)));

__device__ __forceinline__ void gload16(const void* g, void* l) {
    __builtin_amdgcn_global_load_lds(
        (const __attribute__((address_space(1))) void*)g,
        (__attribute__((address_space(3))) void*)l,
        16, 0, 0);
}

// counted-vmcnt barrier: newest N loads may stay in flight; everything older done.
#define PIPE_BARRIER(N)                                              \
    asm volatile("s_waitcnt vmcnt(" #N ") lgkmcnt(0)" ::: "memory"); \
    __builtin_amdgcn_sched_barrier(0);                               \
    __builtin_amdgcn_s_barrier();                                    \
    __builtin_amdgcn_sched_barrier(0);

// padded gate-weight LDS index: bank-conflict-free for e-parallel f4 reads
__device__ __forceinline__ int sgwIdx(int e, int h) {
    return e * 1056 + h + ((h >> 7) << 2);
}

// ---------------- Router: one wave per token; also converts x -> bf16 xb ----------------
__global__ __launch_bounds__(256) void router_kernel(
    const float* __restrict__ x, const float* __restrict__ gw,
    int* __restrict__ sel, float* __restrict__ wt, int* __restrict__ counts,
    __bf16* __restrict__ xb)
{
    __shared__ float sgw[NEXP * 1056];  // 33 KB, padded layout
    for (int i = threadIdx.x; i < HID * NEXP; i += 256) {
        int h = i >> 3, e = i & 7;
        sgw[sgwIdx(e, h)] = gw[i];
    }
    __syncthreads();

    const int wave = threadIdx.x >> 6;
    const int lane = threadIdx.x & 63;
    const int t = blockIdx.x * 4 + wave;
    const float* xr = x + (size_t)t * HID;

    // convert this token's row to bf16 (lane handles 16 elems)
    {
        const int c0 = lane * 16;
        float4 v0 = *(const float4*)(xr + c0);
        float4 v1 = *(const float4*)(xr + c0 + 4);
        float4 v2 = *(const float4*)(xr + c0 + 8);
        float4 v3 = *(const float4*)(xr + c0 + 12);
        bf16x8 o0, o1;
        o0[0]=(__bf16)v0.x; o0[1]=(__bf16)v0.y; o0[2]=(__bf16)v0.z; o0[3]=(__bf16)v0.w;
        o0[4]=(__bf16)v1.x; o0[5]=(__bf16)v1.y; o0[6]=(__bf16)v1.z; o0[7]=(__bf16)v1.w;
        o1[0]=(__bf16)v2.x; o1[1]=(__bf16)v2.y; o1[2]=(__bf16)v2.z; o1[3]=(__bf16)v2.w;
        o1[4]=(__bf16)v3.x; o1[5]=(__bf16)v3.y; o1[6]=(__bf16)v3.z; o1[7]=(__bf16)v3.w;
        *(bf16x8*)(xb + (size_t)t * HID + c0) = o0;
        *(bf16x8*)(xb + (size_t)t * HID + c0 + 8) = o1;
    }
    // block 0 also writes the zero pad-row (row index T_TOKENS)
    if (blockIdx.x == 0) {
        bf16x8 z;
        #pragma unroll
        for (int j = 0; j < 8; ++j) z[j] = (__bf16)0.f;
        *(bf16x8*)(xb + (size_t)T_TOKENS * HID + threadIdx.x * 8) = z;
    }

    const int e = lane & 7;
    const int c = lane >> 3;       // 128-h chunk
    float acc = 0.f;
    #pragma unroll
    for (int h = c * 128; h < c * 128 + 128; h += 4) {
        float4 xv = *(const float4*)(xr + h);
        float4 wv = *(const float4*)&sgw[sgwIdx(e, h)];
        acc += xv.x * wv.x + xv.y * wv.y + xv.z * wv.z + xv.w * wv.w;
    }
    acc += __shfl_xor(acc, 8);
    acc += __shfl_xor(acc, 16);
    acc += __shfl_xor(acc, 32);
    float m = acc;
    #pragma unroll
    for (int d = 1; d < 8; d <<= 1) m = fmaxf(m, __shfl_xor(m, d));
    float p = expf(acc - m);
    float s = p;
    #pragma unroll
    for (int d = 1; d < 8; d <<= 1) s += __shfl_xor(s, d);
    p /= s;
    float p1 = p; int e1 = e;
    #pragma unroll
    for (int d = 1; d < 8; d <<= 1) {
        float op = __shfl_xor(p1, d); int oe = __shfl_xor(e1, d);
        if (op > p1 || (op == p1 && oe < e1)) { p1 = op; e1 = oe; }
    }
    float pm = (e == e1) ? -1.0f : p;
    float p2 = pm; int e2 = e;
    #pragma unroll
    for (int d = 1; d < 8; d <<= 1) {
        float op = __shfl_xor(p2, d); int oe = __shfl_xor(e2, d);
        if (op > p2 || (op == p2 && oe < e2)) { p2 = op; e2 = oe; }
    }
    if (lane == 0) {
        float inv = 1.0f / (p1 + p2);
        sel[t * 2 + 0] = e1; sel[t * 2 + 1] = e2;
        wt[t * 2 + 0] = p1 * inv; wt[t * 2 + 1] = p2 * inv;
        atomicAdd(&counts[e1], 1); atomicAdd(&counts[e2], 1);
    }
}

// ---------------- Scan + assign + tile table (single block) ----------------
__global__ __launch_bounds__(256) void scan_assign_kernel(
    const int* __restrict__ counts, int* __restrict__ tiles,
    const int* __restrict__ sel, const float* __restrict__ wt,
    int* __restrict__ rtok, float* __restrict__ rwt, int* __restrict__ tok2row)
{
    __shared__ int soff[NEXP];
    __shared__ int scur[NEXP];
    if (threadIdx.x == 0) {
        int cur = 0, tix = 0;
        for (int e = 0; e < NEXP; ++e) {
            soff[e] = cur; scur[e] = 0;
            int n64 = (counts[e] + 63) & ~63;          // 64-row tile alignment
            for (int rt = 0; rt * 64 < n64; ++rt)
                tiles[tix++] = (e << 16) | (cur + rt * 64);
            cur += n64;
        }
        for (; tix < TILES_MAX; ++tix) tiles[tix] = -1;
    }
    __syncthreads();
    for (int t = threadIdx.x; t < T_TOKENS; t += 256) {
        #pragma unroll
        for (int k = 0; k < 2; ++k) {
            int e = sel[t * 2 + k];
            int pos = atomicAdd(&scur[e], 1);
            int row = soff[e] + pos;
            rtok[row] = t + 1;          // sentinel: 0 = pad row
            rwt[row] = wt[t * 2 + k];
            tok2row[t * 2 + k] = row;
        }
    }
}

// ---------------- Fused transpose+convert for all 3 weights ----------------
__global__ __launch_bounds__(256) void tcvt_all_kernel(
    const float* __restrict__ wg, const float* __restrict__ wu, const float* __restrict__ wd,
    __bf16* __restrict__ wgT, __bf16* __restrict__ wuT, __bf16* __restrict__ wdT)
{
    const int z = blockIdx.z;
    const int e = z & 7;
    const float* in;
    __bf16* out;
    int R, C, r0, c0;
    if (z < 16) {
        R = HID; C = ISZ;
        r0 = blockIdx.y * 64; c0 = blockIdx.x * 64;
        in  = (z < 8 ? wg : wu)  + (size_t)e * R * C;
        out = (z < 8 ? wgT : wuT) + (size_t)e * R * C;
    } else {
        R = ISZ; C = HID;
        r0 = blockIdx.x * 64; c0 = blockIdx.y * 64;
        in  = wd  + (size_t)e * R * C;
        out = wdT + (size_t)e * R * C;
    }
    __shared__ float t[64][65];
    const int tid = threadIdx.x;
    const int lr  = tid >> 4;
    const int lc4 = (tid & 15) * 4;
    #pragma unroll
    for (int p = 0; p < 4; ++p) {
        float4 v = *(const float4*)(in + (size_t)(r0 + p * 16 + lr) * C + c0 + lc4);
        t[p * 16 + lr][lc4 + 0] = v.x;
        t[p * 16 + lr][lc4 + 1] = v.y;
        t[p * 16 + lr][lc4 + 2] = v.z;
        t[p * 16 + lr][lc4 + 3] = v.w;
    }
    __syncthreads();
    #pragma unroll
    for (int p = 0; p < 4; ++p) {
        int oc = p * 16 + lr;
        bf16x4 w;
        #pragma unroll
        for (int j = 0; j < 4; ++j) w[j] = (__bf16)t[lc4 + j][oc];
        *(bf16x4*)(out + (size_t)(c0 + oc) * R + r0 + lc4) = w;
    }
}

// ---------------- FFN1: inter = silu(x@WgT') * (x@WuT') ----------------
// BM=64, BN=64(G)+64(U), BK=32, 32x32x16 MFMA, 4 waves 2x2 (each 32r x 32c of G AND U).
// 4-buf depth-3 counted-vmcnt pipeline (3 loads/stage, vmcnt(6)). 48 KB -> 3 blocks/CU.
// Tile-table grid: only live tiles dispatched; panel-major XCD chunks.
__global__ __launch_bounds__(256) void ffn1_kernel(
    const __bf16* __restrict__ xb, const int* __restrict__ rtok,
    const __bf16* __restrict__ wgT, const __bf16* __restrict__ wuT,
    const int* __restrict__ tiles, __bf16* __restrict__ inter)
{
    // grid 1584 = 22 stripes x 72 tiles; XCD chunks of 198 (panel-major within chunk)
    const int n  = blockIdx.x;
    const int nn = (n & 7) * 198 + (n >> 3);
    const int i0 = (nn / TILES_MAX) * 64;      // stripe 0..21
    const int tv = tiles[nn % TILES_MAX];
    if (tv < 0) return;
    const int e = tv >> 16;
    const int rowbase = tv & 0xFFFF;

    __shared__ __align__(16) __bf16 sA[4][64][32];  // 16 KB
    __shared__ __align__(16) __bf16 sG[4][64][32];  // 16 KB
    __shared__ __align__(16) __bf16 sU[4][64][32];  // 16 KB -> 48 KB

    const int lane = threadIdx.x & 63;
    const int wid  = threadIdx.x >> 6;
    const int wr = wid >> 1, wc = wid & 1;
    const int l31 = lane & 31;
    const int kg  = lane >> 5;                 // k-half 0/1

    // staging: gload16 covers 16 rows x 64B; lane: row = lane>>2, slot = lane&3.
    // slot s at row R holds global chunk s ^ ((R>>1)&3)  (involution).
    const int r16 = lane >> 2;
    const int cz  = (((lane & 3) ^ ((r16 >> 1) & 3)) * 8);
    const int rowA = rowbase + wid * 16 + r16;
    const int tokp = rtok[rowA];
    const int src  = tokp ? (tokp - 1) : T_TOKENS;     // pad rows -> zero row
    const __bf16* A0 = xb + (size_t)src * HID + cz;
    const size_t wb = (size_t)e * ISZ * HID + (size_t)(i0 + wid * 16 + r16) * HID + cz;
    const __bf16* G0 = wgT + wb;
    const __bf16* U0 = wuT + wb;

    f32x16 accG, accU;
    #pragma unroll
    for (int r = 0; r < 16; ++r) { accG[r] = 0.f; accU[r] = 0.f; }

    auto stage = [&](int b, int k0) {   // 3 gload16 per wave
        gload16(A0 + k0, &sA[b][wid * 16][0]);
        gload16(G0 + k0, &sG[b][wid * 16][0]);
        gload16(U0 + k0, &sU[b][wid * 16][0]);
    };
    auto compute = [&](int b) {
        #pragma unroll
        for (int s = 0; s < 2; ++s) {
            const int ch = ((2 * s + kg) ^ ((l31 >> 1) & 3)) * 8;
            bf16x8 a_ = *(const bf16x8*)&sA[b][wr * 32 + l31][ch];
            bf16x8 g_ = *(const bf16x8*)&sG[b][wc * 32 + l31][ch];
            bf16x8 u_ = *(const bf16x8*)&sU[b][wc * 32 + l31][ch];
            __builtin_amdgcn_s_setprio(1);
            accG = __builtin_amdgcn_mfma_f32_32x32x16_bf16(a_, g_, accG, 0, 0, 0);
            accU = __builtin_amdgcn_mfma_f32_32x32x16_bf16(a_, u_, accU, 0, 0, 0);
            __builtin_amdgcn_s_setprio(0);
        }
    };

    const int nIter = HID / 32;   // 32
    stage(0, 0);
    stage(1, 32);
    stage(2, 64);
    PIPE_BARRIER(6)               // stage0 landed; stages 1,2 (6 loads) in flight
    for (int i = 0; i < nIter; ++i) {
        int ks = (i + 3 < nIter) ? (i + 3) * 32 : 0;   // clamped dead stage keeps counts uniform
        stage((i + 3) & 3, ks);
        compute(i & 3);
        PIPE_BARRIER(6)           // stage(i+1) landed; newest 2 stages in flight
    }

    // epilogue: silu(G)*U -> bf16 inter (D: col = lane&31, row = (r&3)+8*(r>>2)+4*kg)
    const int base_row = rowbase + wr * 32;
    #pragma unroll
    for (int r = 0; r < 16; ++r) {
        float g = accG[r];
        float u = accU[r];
        float v = g / (1.0f + __expf(-g)) * u;
        int row = base_row + (r & 3) + 8 * (r >> 2) + 4 * kg;
        inter[(size_t)row * ISZ + i0 + wc * 32 + l31] = (__bf16)v;
    }
}

// ---------------- FFN2: y[row] = rwt[row] * (inter[row] @ WdT')  (no atomics) ----------------
// BM=64, BN=64, BK=32, 4 waves 2x2 (each 32x32). 4-buf depth-3, vmcnt(4). 32 KB -> 5 blocks/CU.
__global__ __launch_bounds__(256) void ffn2_kernel(
    const __bf16* __restrict__ inter, const __bf16* __restrict__ wdT,
    const float* __restrict__ rwt, const int* __restrict__ tiles,
    float* __restrict__ y)
{
    // grid 1152 = 16 stripes x 72 tiles; XCD chunks of 144
    const int n  = blockIdx.x;
    const int nn = (n & 7) * 144 + (n >> 3);
    const int n0 = (nn / TILES_MAX) * 64;      // stripe 0..15
    const int tv = tiles[nn % TILES_MAX];
    if (tv < 0) return;
    const int e = tv >> 16;
    const int rowbase = tv & 0xFFFF;

    __shared__ __align__(16) __bf16 sA[4][64][32];  // 16 KB
    __shared__ __align__(16) __bf16 sB[4][64][32];  // 16 KB -> 32 KB

    const int lane = threadIdx.x & 63;
    const int wid  = threadIdx.x >> 6;
    const int wr = wid >> 1, wc = wid & 1;
    const int l31 = lane & 31;
    const int kg  = lane >> 5;

    const int r16 = lane >> 2;
    const int cz  = (((lane & 3) ^ ((r16 >> 1) & 3)) * 8);
    const __bf16* A0 = inter + (size_t)(rowbase + wid * 16 + r16) * ISZ + cz;
    const __bf16* B0 = wdT + (size_t)e * HID * ISZ + (size_t)(n0 + wid * 16 + r16) * ISZ + cz;

    f32x16 acc;
    #pragma unroll
    for (int r = 0; r < 16; ++r) acc[r] = 0.f;

    auto stage = [&](int b, int k0) {   // 2 gload16 per wave
        gload16(A0 + k0, &sA[b][wid * 16][0]);
        gload16(B0 + k0, &sB[b][wid * 16][0]);
    };
    auto compute = [&](int b) {
        #pragma unroll
        for (int s = 0; s < 2; ++s) {
            const int ch = ((2 * s + kg) ^ ((l31 >> 1) & 3)) * 8;
            bf16x8 a_ = *(const bf16x8*)&sA[b][wr * 32 + l31][ch];
            bf16x8 b_ = *(const bf16x8*)&sB[b][wc * 32 + l31][ch];
            __builtin_amdgcn_s_setprio(1);
            acc = __builtin_amdgcn_mfma_f32_32x32x16_bf16(a_, b_, acc, 0, 0, 0);
            __builtin_amdgcn_s_setprio(0);
        }
    };

    const int nIter = ISZ / 32;   // 44
    stage(0, 0);
    stage(1, 32);
    stage(2, 64);
    PIPE_BARRIER(4)
    for (int i = 0; i < nIter; ++i) {
        int ks = (i + 3 < nIter) ? (i + 3) * 32 : 0;
        stage((i + 3) & 3, ks);
        compute(i & 3);
        PIPE_BARRIER(4)
    }

    const int base_row = rowbase + wr * 32;
    const int col = n0 + wc * 32 + l31;
    #pragma unroll
    for (int r = 0; r < 16; ++r) {
        int row = base_row + (r & 3) + 8 * (r >> 2) + 4 * kg;
        y[(size_t)row * HID + col] = rwt[row] * acc[r];
    }
}

// ---------------- Combine: out[t] = y[row0(t)] + y[row1(t)] ----------------
__global__ __launch_bounds__(256) void combine_kernel(
    const float* __restrict__ y, const int* __restrict__ tok2row, float* __restrict__ out)
{
    const int idx = blockIdx.x * 256 + threadIdx.x;
    const int t = idx >> 8;
    const int c = (idx & 255) * 4;
    const int r0 = tok2row[t * 2];
    const int r1 = tok2row[t * 2 + 1];
    float4 a = *(const float4*)(y + (size_t)r0 * HID + c);
    float4 b = *(const float4*)(y + (size_t)r1 * HID + c);
    float4 o = {a.x + b.x, a.y + b.y, a.z + b.z, a.w + b.w};
    *(float4*)(out + (size_t)t * HID + c) = o;
}

extern "C" void kernel_launch(void* const* d_in, const int* in_sizes, int n_in,
                              void* d_out, int out_size, void* d_ws, size_t ws_size,
                              hipStream_t stream) {
    const float* x  = (const float*)d_in[0];
    const float* gw = (const float*)d_in[1];
    const float* wg = (const float*)d_in[2];
    const float* wu = (const float*)d_in[3];
    const float* wd = (const float*)d_in[4];
    float* out = (float*)d_out;

    char* ws = (char*)d_ws;
    int*    counts  = (int*)(ws + 0);            // 32 B
    int*    tiles   = (int*)(ws + 64);           // 72 ints
    int*    sel     = (int*)(ws + 1024);         // 4096 ints
    float*  wtp     = (float*)(ws + 17408);      // 4096 f32
    int*    rtok    = (int*)(ws + 33792);        // 4608 ints
    float*  rwt     = (float*)(ws + 52224);      // 4608 f32
    int*    tok2row = (int*)(ws + 70656);        // 4096 ints -> ends 87040
    __bf16* xb      = (__bf16*)(ws + 87040);     // 2049*1024 bf16 = 4.20 MB
    __bf16* inter   = (__bf16*)(ws + 4283648);   // 4608*1408 bf16 = 12.98 MB
    __bf16* wgT     = (__bf16*)(ws + 17260032);  // 23.07 MB
    __bf16* wuT     = (__bf16*)(ws + 40328704);  // 23.07 MB
    __bf16* wdT     = (__bf16*)(ws + 63397376);  // 23.07 MB -> ends 86.5 MB
    float*  y       = (float*)wgT;               // alias: wgT dead after ffn1 (18.9 MB <= 23.07)

    // one merged zero-fill: counts + tiles + rtok (sentinel 0 = pad) + rwt + headers
    hipMemsetAsync(ws, 0, 87040, stream);

    tcvt_all_kernel<<<dim3(ISZ / 64, HID / 64, 24), 256, 0, stream>>>(wg, wu, wd, wgT, wuT, wdT);

    router_kernel<<<T_TOKENS / 4, 256, 0, stream>>>(x, gw, sel, wtp, counts, xb);
    scan_assign_kernel<<<1, 256, 0, stream>>>(counts, tiles, sel, wtp, rtok, rwt, tok2row);

    ffn1_kernel<<<22 * TILES_MAX, 256, 0, stream>>>(xb, rtok, wgT, wuT, tiles, inter);  // 1584
    ffn2_kernel<<<16 * TILES_MAX, 256, 0, stream>>>(inter, wdT, rwt, tiles, y);         // 1152
    combine_kernel<<<(T_TOKENS * HID / 4) / 256, 256, 0, stream>>>(y, tok2row, out);
}

// Round 15
// 156.230 us; speedup vs baseline: 1.5614x; 1.2837x over previous
//
#include <hip/hip_runtime.h>
#include <hip/hip_bf16.h>

#define T_TOKENS 2048
#define HID 1024
#define ISZ 1408
#define NEXP 8
#define RMAXROWS 4608   // sum of 64-aligned expert counts <= 4096 + 8*63
#define TILES_MAX 72    // sum ceil(cnt_e/64) <= 4096/64 + 8 = 72

typedef __bf16 bf16x8 __attribute__((ext_vector_type(8)));
typedef __bf16 bf16x4 __attribute__((ext_vector_type(4)));
typedef float  f32x16 __attribute__((ext_vector_type(16)));

__device__ __forceinline__ void gload16(const void* g, void* l) {
    __builtin_amdgcn_global_load_lds(
        (const __attribute__((address_space(1))) void*)g,
        (__attribute__((address_space(3))) void*)l,
        16, 0, 0);
}

// counted-vmcnt barrier: newest N loads may stay in flight; everything older done.
#define PIPE_BARRIER(N)                                              \
    asm volatile("s_waitcnt vmcnt(" #N ") lgkmcnt(0)" ::: "memory"); \
    __builtin_amdgcn_sched_barrier(0);                               \
    __builtin_amdgcn_s_barrier();                                    \
    __builtin_amdgcn_sched_barrier(0);

// gate-weight LDS layout: idx = e*1032 + h + (h>>7)
// injective: max per-e offset 1030 < 1032. banks: (8*(e&3) + 4j + c) % 32
// -> each bank hit by exactly 2 lanes (e and e+4) = free (2-way).
__device__ __forceinline__ int sgwIdx(int e, int h) {
    return e * 1032 + h + (h >> 7);
}

// ---------------- Router: one wave per token; NO global atomics ----------------
__global__ __launch_bounds__(256) void router_kernel(
    const float* __restrict__ x, const float* __restrict__ gw,
    int* __restrict__ sel, float* __restrict__ wt,
    __bf16* __restrict__ xb)
{
    __shared__ float sgw[NEXP * 1032 + 8];  // ~33 KB
    for (int i = threadIdx.x; i < HID * NEXP; i += 256) {
        int h = i >> 3, e = i & 7;
        sgw[sgwIdx(e, h)] = gw[i];
    }
    __syncthreads();

    const int wave = threadIdx.x >> 6;
    const int lane = threadIdx.x & 63;
    const int t = blockIdx.x * 4 + wave;
    const float* xr = x + (size_t)t * HID;

    // convert this token's row to bf16 (lane handles 16 elems)
    {
        const int c0 = lane * 16;
        float4 v0 = *(const float4*)(xr + c0);
        float4 v1 = *(const float4*)(xr + c0 + 4);
        float4 v2 = *(const float4*)(xr + c0 + 8);
        float4 v3 = *(const float4*)(xr + c0 + 12);
        bf16x8 o0, o1;
        o0[0]=(__bf16)v0.x; o0[1]=(__bf16)v0.y; o0[2]=(__bf16)v0.z; o0[3]=(__bf16)v0.w;
        o0[4]=(__bf16)v1.x; o0[5]=(__bf16)v1.y; o0[6]=(__bf16)v1.z; o0[7]=(__bf16)v1.w;
        o1[0]=(__bf16)v2.x; o1[1]=(__bf16)v2.y; o1[2]=(__bf16)v2.z; o1[3]=(__bf16)v2.w;
        o1[4]=(__bf16)v3.x; o1[5]=(__bf16)v3.y; o1[6]=(__bf16)v3.z; o1[7]=(__bf16)v3.w;
        *(bf16x8*)(xb + (size_t)t * HID + c0) = o0;
        *(bf16x8*)(xb + (size_t)t * HID + c0 + 8) = o1;
    }
    // block 0, first 128 threads write the zero pad-row (row index T_TOKENS, HID elems)
    if (blockIdx.x == 0 && threadIdx.x < 128) {
        bf16x8 z;
        #pragma unroll
        for (int j = 0; j < 8; ++j) z[j] = (__bf16)0.f;
        *(bf16x8*)(xb + (size_t)T_TOKENS * HID + threadIdx.x * 8) = z;
    }

    const int e = lane & 7;
    const int c = lane >> 3;       // 128-h chunk
    float acc = 0.f;
    #pragma unroll
    for (int h = c * 128; h < c * 128 + 128; h += 4) {
        float4 xv = *(const float4*)(xr + h);
        float4 wv = *(const float4*)&sgw[sgwIdx(e, h)];
        acc += xv.x * wv.x + xv.y * wv.y + xv.z * wv.z + xv.w * wv.w;
    }
    acc += __shfl_xor(acc, 8);
    acc += __shfl_xor(acc, 16);
    acc += __shfl_xor(acc, 32);
    float m = acc;
    #pragma unroll
    for (int d = 1; d < 8; d <<= 1) m = fmaxf(m, __shfl_xor(m, d));
    float p = expf(acc - m);
    float s = p;
    #pragma unroll
    for (int d = 1; d < 8; d <<= 1) s += __shfl_xor(s, d);
    p /= s;
    float p1 = p; int e1 = e;
    #pragma unroll
    for (int d = 1; d < 8; d <<= 1) {
        float op = __shfl_xor(p1, d); int oe = __shfl_xor(e1, d);
        if (op > p1 || (op == p1 && oe < e1)) { p1 = op; e1 = oe; }
    }
    float pm = (e == e1) ? -1.0f : p;
    float p2 = pm; int e2 = e;
    #pragma unroll
    for (int d = 1; d < 8; d <<= 1) {
        float op = __shfl_xor(p2, d); int oe = __shfl_xor(e2, d);
        if (op > p2 || (op == p2 && oe < e2)) { p2 = op; e2 = oe; }
    }
    if (lane == 0) {
        float inv = 1.0f / (p1 + p2);
        sel[t * 2 + 0] = e1; sel[t * 2 + 1] = e2;
        wt[t * 2 + 0] = p1 * inv; wt[t * 2 + 1] = p2 * inv;
    }
}

// ---------------- Histogram + scan + assign + tile table (single block) ----------------
__global__ __launch_bounds__(256) void scan_assign_kernel(
    int* __restrict__ tiles,
    const int* __restrict__ sel, const float* __restrict__ wt,
    int* __restrict__ rtok, float* __restrict__ rwt, int* __restrict__ tok2row)
{
    __shared__ int hist[NEXP];
    __shared__ int soff[NEXP];
    __shared__ int scur[NEXP];
    if (threadIdx.x < NEXP) { hist[threadIdx.x] = 0; scur[threadIdx.x] = 0; }
    __syncthreads();
    // LDS histogram of expert selections
    for (int t = threadIdx.x; t < T_TOKENS; t += 256) {
        atomicAdd(&hist[sel[t * 2 + 0]], 1);
        atomicAdd(&hist[sel[t * 2 + 1]], 1);
    }
    __syncthreads();
    if (threadIdx.x == 0) {
        int cur = 0, tix = 0;
        for (int e = 0; e < NEXP; ++e) {
            soff[e] = cur;
            int n64 = (hist[e] + 63) & ~63;            // 64-row tile alignment
            for (int rt = 0; rt * 64 < n64; ++rt)
                tiles[tix++] = (e << 16) | (cur + rt * 64);
            cur += n64;
        }
        for (; tix < TILES_MAX; ++tix) tiles[tix] = -1;
    }
    __syncthreads();
    for (int t = threadIdx.x; t < T_TOKENS; t += 256) {
        #pragma unroll
        for (int k = 0; k < 2; ++k) {
            int e = sel[t * 2 + k];
            int pos = atomicAdd(&scur[e], 1);
            int row = soff[e] + pos;
            rtok[row] = t + 1;          // sentinel: 0 = pad row
            rwt[row] = wt[t * 2 + k];
            tok2row[t * 2 + k] = row;
        }
    }
}

// ---------------- Fused transpose+convert for all 3 weights ----------------
__global__ __launch_bounds__(256) void tcvt_all_kernel(
    const float* __restrict__ wg, const float* __restrict__ wu, const float* __restrict__ wd,
    __bf16* __restrict__ wgT, __bf16* __restrict__ wuT, __bf16* __restrict__ wdT)
{
    const int z = blockIdx.z;
    const int e = z & 7;
    const float* in;
    __bf16* out;
    int R, C, r0, c0;
    if (z < 16) {
        R = HID; C = ISZ;
        r0 = blockIdx.y * 64; c0 = blockIdx.x * 64;
        in  = (z < 8 ? wg : wu)  + (size_t)e * R * C;
        out = (z < 8 ? wgT : wuT) + (size_t)e * R * C;
    } else {
        R = ISZ; C = HID;
        r0 = blockIdx.x * 64; c0 = blockIdx.y * 64;
        in  = wd  + (size_t)e * R * C;
        out = wdT + (size_t)e * R * C;
    }
    __shared__ float t[64][65];
    const int tid = threadIdx.x;
    const int lr  = tid >> 4;
    const int lc4 = (tid & 15) * 4;
    #pragma unroll
    for (int p = 0; p < 4; ++p) {
        float4 v = *(const float4*)(in + (size_t)(r0 + p * 16 + lr) * C + c0 + lc4);
        t[p * 16 + lr][lc4 + 0] = v.x;
        t[p * 16 + lr][lc4 + 1] = v.y;
        t[p * 16 + lr][lc4 + 2] = v.z;
        t[p * 16 + lr][lc4 + 3] = v.w;
    }
    __syncthreads();
    #pragma unroll
    for (int p = 0; p < 4; ++p) {
        int oc = p * 16 + lr;
        bf16x4 w;
        #pragma unroll
        for (int j = 0; j < 4; ++j) w[j] = (__bf16)t[lc4 + j][oc];
        *(bf16x4*)(out + (size_t)(c0 + oc) * R + r0 + lc4) = w;
    }
}

// ---------------- FFN1: inter = silu(x@WgT') * (x@WuT') ----------------
// BM=64, BN=64(G)+64(U), BK=32, 32x32x16 MFMA, 4 waves 2x2 (each 32r x 32c of G AND U).
// 4-buf depth-3 counted-vmcnt pipeline (3 loads/stage, vmcnt(6)). 48 KB -> 3 blocks/CU.
// Tile-table grid: only live tiles dispatched; XCD-chunked.
__global__ __launch_bounds__(256) void ffn1_kernel(
    const __bf16* __restrict__ xb, const int* __restrict__ rtok,
    const __bf16* __restrict__ wgT, const __bf16* __restrict__ wuT,
    const int* __restrict__ tiles, __bf16* __restrict__ inter)
{
    // grid 1584 = 22 stripes x 72 tiles; XCD chunks of 198
    const int n  = blockIdx.x;
    const int nn = (n & 7) * 198 + (n >> 3);
    const int i0 = (nn / TILES_MAX) * 64;      // stripe 0..21
    const int tv = tiles[nn % TILES_MAX];
    if (tv < 0) return;
    const int e = tv >> 16;
    const int rowbase = tv & 0xFFFF;

    __shared__ __align__(16) __bf16 sA[4][64][32];  // 16 KB
    __shared__ __align__(16) __bf16 sG[4][64][32];  // 16 KB
    __shared__ __align__(16) __bf16 sU[4][64][32];  // 16 KB -> 48 KB

    const int lane = threadIdx.x & 63;
    const int wid  = threadIdx.x >> 6;
    const int wr = wid >> 1, wc = wid & 1;
    const int l31 = lane & 31;
    const int kg  = lane >> 5;                 // k-half 0/1

    // staging: gload16 covers 16 rows x 64B; lane: row = lane>>2, slot = lane&3.
    // slot s at row R holds global chunk s ^ ((R>>1)&3)  (involution).
    const int r16 = lane >> 2;
    const int cz  = (((lane & 3) ^ ((r16 >> 1) & 3)) * 8);
    const int rowA = rowbase + wid * 16 + r16;
    const int tokp = rtok[rowA];
    const int src  = tokp ? (tokp - 1) : T_TOKENS;     // pad rows -> zero row
    const __bf16* A0 = xb + (size_t)src * HID + cz;
    const size_t wb = (size_t)e * ISZ * HID + (size_t)(i0 + wid * 16 + r16) * HID + cz;
    const __bf16* G0 = wgT + wb;
    const __bf16* U0 = wuT + wb;

    f32x16 accG, accU;
    #pragma unroll
    for (int r = 0; r < 16; ++r) { accG[r] = 0.f; accU[r] = 0.f; }

    auto stage = [&](int b, int k0) {   // 3 gload16 per wave
        gload16(A0 + k0, &sA[b][wid * 16][0]);
        gload16(G0 + k0, &sG[b][wid * 16][0]);
        gload16(U0 + k0, &sU[b][wid * 16][0]);
    };
    auto compute = [&](int b) {
        #pragma unroll
        for (int s = 0; s < 2; ++s) {
            const int ch = ((2 * s + kg) ^ ((l31 >> 1) & 3)) * 8;
            bf16x8 a_ = *(const bf16x8*)&sA[b][wr * 32 + l31][ch];
            bf16x8 g_ = *(const bf16x8*)&sG[b][wc * 32 + l31][ch];
            bf16x8 u_ = *(const bf16x8*)&sU[b][wc * 32 + l31][ch];
            __builtin_amdgcn_s_setprio(1);
            accG = __builtin_amdgcn_mfma_f32_32x32x16_bf16(a_, g_, accG, 0, 0, 0);
            accU = __builtin_amdgcn_mfma_f32_32x32x16_bf16(a_, u_, accU, 0, 0, 0);
            __builtin_amdgcn_s_setprio(0);
        }
    };

    const int nIter = HID / 32;   // 32
    stage(0, 0);
    stage(1, 32);
    stage(2, 64);
    PIPE_BARRIER(6)               // stage0 landed; stages 1,2 (6 loads) in flight
    for (int i = 0; i < nIter; ++i) {
        int ks = (i + 3 < nIter) ? (i + 3) * 32 : 0;   // clamped dead stage keeps counts uniform
        stage((i + 3) & 3, ks);
        compute(i & 3);
        PIPE_BARRIER(6)           // stage(i+1) landed; newest 2 stages in flight
    }

    // epilogue: silu(G)*U -> bf16 inter (D: col = lane&31, row = (r&3)+8*(r>>2)+4*kg)
    const int base_row = rowbase + wr * 32;
    #pragma unroll
    for (int r = 0; r < 16; ++r) {
        float g = accG[r];
        float u = accU[r];
        float v = g / (1.0f + __expf(-g)) * u;
        int row = base_row + (r & 3) + 8 * (r >> 2) + 4 * kg;
        inter[(size_t)row * ISZ + i0 + wc * 32 + l31] = (__bf16)v;
    }
}

// ---------------- FFN2: y[row] = rwt[row] * (inter[row] @ WdT')  (no atomics) ----------------
// BM=64, BN=64, BK=32, 4 waves 2x2 (each 32x32). 4-buf depth-3, vmcnt(4). 32 KB -> 5 blocks/CU.
__global__ __launch_bounds__(256) void ffn2_kernel(
    const __bf16* __restrict__ inter, const __bf16* __restrict__ wdT,
    const float* __restrict__ rwt, const int* __restrict__ tiles,
    float* __restrict__ y)
{
    // grid 1152 = 16 stripes x 72 tiles; XCD chunks of 144
    const int n  = blockIdx.x;
    const int nn = (n & 7) * 144 + (n >> 3);
    const int n0 = (nn / TILES_MAX) * 64;      // stripe 0..15
    const int tv = tiles[nn % TILES_MAX];
    if (tv < 0) return;
    const int e = tv >> 16;
    const int rowbase = tv & 0xFFFF;

    __shared__ __align__(16) __bf16 sA[4][64][32];  // 16 KB
    __shared__ __align__(16) __bf16 sB[4][64][32];  // 16 KB -> 32 KB

    const int lane = threadIdx.x & 63;
    const int wid  = threadIdx.x >> 6;
    const int wr = wid >> 1, wc = wid & 1;
    const int l31 = lane & 31;
    const int kg  = lane >> 5;

    const int r16 = lane >> 2;
    const int cz  = (((lane & 3) ^ ((r16 >> 1) & 3)) * 8);
    const __bf16* A0 = inter + (size_t)(rowbase + wid * 16 + r16) * ISZ + cz;
    const __bf16* B0 = wdT + (size_t)e * HID * ISZ + (size_t)(n0 + wid * 16 + r16) * ISZ + cz;

    f32x16 acc;
    #pragma unroll
    for (int r = 0; r < 16; ++r) acc[r] = 0.f;

    auto stage = [&](int b, int k0) {   // 2 gload16 per wave
        gload16(A0 + k0, &sA[b][wid * 16][0]);
        gload16(B0 + k0, &sB[b][wid * 16][0]);
    };
    auto compute = [&](int b) {
        #pragma unroll
        for (int s = 0; s < 2; ++s) {
            const int ch = ((2 * s + kg) ^ ((l31 >> 1) & 3)) * 8;
            bf16x8 a_ = *(const bf16x8*)&sA[b][wr * 32 + l31][ch];
            bf16x8 b_ = *(const bf16x8*)&sB[b][wc * 32 + l31][ch];
            __builtin_amdgcn_s_setprio(1);
            acc = __builtin_amdgcn_mfma_f32_32x32x16_bf16(a_, b_, acc, 0, 0, 0);
            __builtin_amdgcn_s_setprio(0);
        }
    };

    const int nIter = ISZ / 32;   // 44
    stage(0, 0);
    stage(1, 32);
    stage(2, 64);
    PIPE_BARRIER(4)
    for (int i = 0; i < nIter; ++i) {
        int ks = (i + 3 < nIter) ? (i + 3) * 32 : 0;
        stage((i + 3) & 3, ks);
        compute(i & 3);
        PIPE_BARRIER(4)
    }

    const int base_row = rowbase + wr * 32;
    const int col = n0 + wc * 32 + l31;
    #pragma unroll
    for (int r = 0; r < 16; ++r) {
        int row = base_row + (r & 3) + 8 * (r >> 2) + 4 * kg;
        y[(size_t)row * HID + col] = rwt[row] * acc[r];
    }
}

// ---------------- Combine: out[t] = y[row0(t)] + y[row1(t)] ----------------
__global__ __launch_bounds__(256) void combine_kernel(
    const float* __restrict__ y, const int* __restrict__ tok2row, float* __restrict__ out)
{
    const int idx = blockIdx.x * 256 + threadIdx.x;
    const int t = idx >> 8;
    const int c = (idx & 255) * 4;
    const int r0 = tok2row[t * 2];
    const int r1 = tok2row[t * 2 + 1];
    float4 a = *(const float4*)(y + (size_t)r0 * HID + c);
    float4 b = *(const float4*)(y + (size_t)r1 * HID + c);
    float4 o = {a.x + b.x, a.y + b.y, a.z + b.z, a.w + b.w};
    *(float4*)(out + (size_t)t * HID + c) = o;
}

extern "C" void kernel_launch(void* const* d_in, const int* in_sizes, int n_in,
                              void* d_out, int out_size, void* d_ws, size_t ws_size,
                              hipStream_t stream) {
    const float* x  = (const float*)d_in[0];
    const float* gw = (const float*)d_in[1];
    const float* wg = (const float*)d_in[2];
    const float* wu = (const float*)d_in[3];
    const float* wd = (const float*)d_in[4];
    float* out = (float*)d_out;

    char* ws = (char*)d_ws;
    int*    tiles   = (int*)(ws + 64);           // 72 ints
    int*    sel     = (int*)(ws + 1024);         // 4096 ints
    float*  wtp     = (float*)(ws + 17408);      // 4096 f32
    int*    rtok    = (int*)(ws + 33792);        // 4608 ints
    float*  rwt     = (float*)(ws + 52224);      // 4608 f32
    int*    tok2row = (int*)(ws + 70656);        // 4096 ints -> ends 87040
    __bf16* xb      = (__bf16*)(ws + 87040);     // 2049*1024 bf16 = 4.20 MB
    __bf16* inter   = (__bf16*)(ws + 4283648);   // 4608*1408 bf16 = 12.98 MB
    __bf16* wgT     = (__bf16*)(ws + 17260032);  // 23.07 MB
    __bf16* wuT     = (__bf16*)(ws + 40328704);  // 23.07 MB
    __bf16* wdT     = (__bf16*)(ws + 63397376);  // 23.07 MB -> ends 86.5 MB
    float*  y       = (float*)wgT;               // alias: wgT dead after ffn1 (18.9 MB <= 23.07)

    // one merged zero-fill: tiles + rtok (sentinel 0 = pad) + rwt + headers
    hipMemsetAsync(ws, 0, 87040, stream);

    tcvt_all_kernel<<<dim3(ISZ / 64, HID / 64, 24), 256, 0, stream>>>(wg, wu, wd, wgT, wuT, wdT);

    router_kernel<<<T_TOKENS / 4, 256, 0, stream>>>(x, gw, sel, wtp, xb);
    scan_assign_kernel<<<1, 256, 0, stream>>>(tiles, sel, wtp, rtok, rwt, tok2row);

    ffn1_kernel<<<22 * TILES_MAX, 256, 0, stream>>>(xb, rtok, wgT, wuT, tiles, inter);  // 1584
    ffn2_kernel<<<16 * TILES_MAX, 256, 0, stream>>>(inter, wdT, rwt, tiles, y);         // 1152
    combine_kernel<<<(T_TOKENS * HID / 4) / 256, 256, 0, stream>>>(y, tok2row, out);
}

// Round 16
// 155.671 us; speedup vs baseline: 1.5670x; 1.0036x over previous
//
#include <hip/hip_runtime.h>
#include <hip/hip_bf16.h>

#define T_TOKENS 2048
#define HID 1024
#define ISZ 1408
#define NEXP 8
#define RMAXROWS 4608   // sum of 64-aligned expert counts <= 4096 + 8*63
#define TILES_MAX 72    // sum ceil(cnt_e/64) <= 4096/64 + 8 = 72

typedef __bf16 bf16x8 __attribute__((ext_vector_type(8)));
typedef __bf16 bf16x4 __attribute__((ext_vector_type(4)));
typedef float  f32x16 __attribute__((ext_vector_type(16)));

__device__ __forceinline__ void gload16(const void* g, void* l) {
    __builtin_amdgcn_global_load_lds(
        (const __attribute__((address_space(1))) void*)g,
        (__attribute__((address_space(3))) void*)l,
        16, 0, 0);
}

// counted-vmcnt barrier: newest N loads may stay in flight; everything older done.
#define PIPE_BARRIER(N)                                              \
    asm volatile("s_waitcnt vmcnt(" #N ") lgkmcnt(0)" ::: "memory"); \
    __builtin_amdgcn_sched_barrier(0);                               \
    __builtin_amdgcn_s_barrier();                                    \
    __builtin_amdgcn_sched_barrier(0);

// gate-weight LDS layout: idx = e*1032 + h + (h>>7)
// injective: max per-e offset 1030 < 1032. banks: (8*(e&3) + 4j + c) % 32
// -> each bank hit by exactly 2 lanes (e and e+4) = free (2-way).
__device__ __forceinline__ int sgwIdx(int e, int h) {
    return e * 1032 + h + (h >> 7);
}

// ---------------- Router: one wave per token; NO global atomics ----------------
__global__ __launch_bounds__(256) void router_kernel(
    const float* __restrict__ x, const float* __restrict__ gw,
    int* __restrict__ sel, float* __restrict__ wt,
    __bf16* __restrict__ xb)
{
    __shared__ float sgw[NEXP * 1032 + 8];  // ~33 KB
    for (int i = threadIdx.x; i < HID * NEXP; i += 256) {
        int h = i >> 3, e = i & 7;
        sgw[sgwIdx(e, h)] = gw[i];
    }
    __syncthreads();

    const int wave = threadIdx.x >> 6;
    const int lane = threadIdx.x & 63;
    const int t = blockIdx.x * 4 + wave;
    const float* xr = x + (size_t)t * HID;

    // convert this token's row to bf16 (lane handles 16 elems)
    {
        const int c0 = lane * 16;
        float4 v0 = *(const float4*)(xr + c0);
        float4 v1 = *(const float4*)(xr + c0 + 4);
        float4 v2 = *(const float4*)(xr + c0 + 8);
        float4 v3 = *(const float4*)(xr + c0 + 12);
        bf16x8 o0, o1;
        o0[0]=(__bf16)v0.x; o0[1]=(__bf16)v0.y; o0[2]=(__bf16)v0.z; o0[3]=(__bf16)v0.w;
        o0[4]=(__bf16)v1.x; o0[5]=(__bf16)v1.y; o0[6]=(__bf16)v1.z; o0[7]=(__bf16)v1.w;
        o1[0]=(__bf16)v2.x; o1[1]=(__bf16)v2.y; o1[2]=(__bf16)v2.z; o1[3]=(__bf16)v2.w;
        o1[4]=(__bf16)v3.x; o1[5]=(__bf16)v3.y; o1[6]=(__bf16)v3.z; o1[7]=(__bf16)v3.w;
        *(bf16x8*)(xb + (size_t)t * HID + c0) = o0;
        *(bf16x8*)(xb + (size_t)t * HID + c0 + 8) = o1;
    }
    // block 0, first 128 threads write the zero pad-row (row index T_TOKENS, HID elems)
    if (blockIdx.x == 0 && threadIdx.x < 128) {
        bf16x8 z;
        #pragma unroll
        for (int j = 0; j < 8; ++j) z[j] = (__bf16)0.f;
        *(bf16x8*)(xb + (size_t)T_TOKENS * HID + threadIdx.x * 8) = z;
    }

    const int e = lane & 7;
    const int c = lane >> 3;       // 128-h chunk
    float acc = 0.f;
    #pragma unroll
    for (int h = c * 128; h < c * 128 + 128; h += 4) {
        float4 xv = *(const float4*)(xr + h);
        float4 wv = *(const float4*)&sgw[sgwIdx(e, h)];
        acc += xv.x * wv.x + xv.y * wv.y + xv.z * wv.z + xv.w * wv.w;
    }
    acc += __shfl_xor(acc, 8);
    acc += __shfl_xor(acc, 16);
    acc += __shfl_xor(acc, 32);
    float m = acc;
    #pragma unroll
    for (int d = 1; d < 8; d <<= 1) m = fmaxf(m, __shfl_xor(m, d));
    float p = expf(acc - m);
    float s = p;
    #pragma unroll
    for (int d = 1; d < 8; d <<= 1) s += __shfl_xor(s, d);
    p /= s;
    float p1 = p; int e1 = e;
    #pragma unroll
    for (int d = 1; d < 8; d <<= 1) {
        float op = __shfl_xor(p1, d); int oe = __shfl_xor(e1, d);
        if (op > p1 || (op == p1 && oe < e1)) { p1 = op; e1 = oe; }
    }
    float pm = (e == e1) ? -1.0f : p;
    float p2 = pm; int e2 = e;
    #pragma unroll
    for (int d = 1; d < 8; d <<= 1) {
        float op = __shfl_xor(p2, d); int oe = __shfl_xor(e2, d);
        if (op > p2 || (op == p2 && oe < e2)) { p2 = op; e2 = oe; }
    }
    if (lane == 0) {
        float inv = 1.0f / (p1 + p2);
        sel[t * 2 + 0] = e1; sel[t * 2 + 1] = e2;
        wt[t * 2 + 0] = p1 * inv; wt[t * 2 + 1] = p2 * inv;
    }
}

// ---------------- Histogram + scan + assign + tile table (single block) ----------------
__global__ __launch_bounds__(256) void scan_assign_kernel(
    int* __restrict__ tiles,
    const int* __restrict__ sel, const float* __restrict__ wt,
    int* __restrict__ rtok, float* __restrict__ rwt, int* __restrict__ tok2row)
{
    __shared__ int hist[NEXP];
    __shared__ int soff[NEXP];
    __shared__ int scur[NEXP];
    if (threadIdx.x < NEXP) { hist[threadIdx.x] = 0; scur[threadIdx.x] = 0; }
    __syncthreads();
    // LDS histogram of expert selections
    for (int t = threadIdx.x; t < T_TOKENS; t += 256) {
        atomicAdd(&hist[sel[t * 2 + 0]], 1);
        atomicAdd(&hist[sel[t * 2 + 1]], 1);
    }
    __syncthreads();
    if (threadIdx.x == 0) {
        int cur = 0, tix = 0;
        for (int e = 0; e < NEXP; ++e) {
            soff[e] = cur;
            int n64 = (hist[e] + 63) & ~63;            // 64-row tile alignment
            for (int rt = 0; rt * 64 < n64; ++rt)
                tiles[tix++] = (e << 16) | (cur + rt * 64);
            cur += n64;
        }
        for (; tix < TILES_MAX; ++tix) tiles[tix] = -1;
    }
    __syncthreads();
    for (int t = threadIdx.x; t < T_TOKENS; t += 256) {
        #pragma unroll
        for (int k = 0; k < 2; ++k) {
            int e = sel[t * 2 + k];
            int pos = atomicAdd(&scur[e], 1);
            int row = soff[e] + pos;
            rtok[row] = t + 1;          // sentinel: 0 = pad row
            rwt[row] = wt[t * 2 + k];
            tok2row[t * 2 + k] = row;
        }
    }
}

// ---------------- Fused transpose+convert, 2-tile pipelined, bf16-LDS ----------------
// grid dim3(11, 16, 24): each block does TWO 64x64 tiles (paired along blockIdx.x axis).
// per tile: load f4 -> cvt -> ds_write_b64 (4); store: 8 scalar b16 reads -> 16B store (2).
__global__ __launch_bounds__(256) void tcvt_all_kernel(
    const float* __restrict__ wg, const float* __restrict__ wu, const float* __restrict__ wd,
    __bf16* __restrict__ wgT, __bf16* __restrict__ wuT, __bf16* __restrict__ wdT)
{
    const int z = blockIdx.z;
    const int e = z & 7;
    const float* in;
    __bf16* out;
    int R, C, rrA, ccA, rrB, ccB;
    if (z < 16) {
        R = HID; C = ISZ;
        rrA = rrB = blockIdx.y * 64;
        ccA = (2 * blockIdx.x) * 64; ccB = ccA + 64;
        in  = (z < 8 ? wg : wu)  + (size_t)e * R * C;
        out = (z < 8 ? wgT : wuT) + (size_t)e * R * C;
    } else {
        R = ISZ; C = HID;
        ccA = ccB = blockIdx.y * 64;
        rrA = (2 * blockIdx.x) * 64; rrB = rrA + 64;
        in  = wd  + (size_t)e * R * C;
        out = wdT + (size_t)e * R * C;
    }
    __shared__ __bf16 tb[2][64][70];   // 17.9 KB
    const int tid = threadIdx.x;
    const int lr  = tid >> 4;          // 0..15
    const int lc4 = (tid & 15) * 4;

    auto loadcvt = [&](int buf, int rr, int cc) {
        #pragma unroll
        for (int p = 0; p < 4; ++p) {
            float4 v = *(const float4*)(in + (size_t)(rr + p * 16 + lr) * C + cc + lc4);
            bf16x4 w;
            w[0] = (__bf16)v.x; w[1] = (__bf16)v.y; w[2] = (__bf16)v.z; w[3] = (__bf16)v.w;
            *(bf16x4*)&tb[buf][p * 16 + lr][lc4] = w;   // 8B vector LDS write
        }
    };
    auto storeT = [&](int buf, int rr, int cc) {
        #pragma unroll
        for (int q = 0; q < 2; ++q) {
            const int oc = (tid >> 3) + 32 * q;   // out row local (= in col) 0..63
            const int vs = (tid & 7) * 8;         // out col local (= in row) base
            bf16x8 w;
            #pragma unroll
            for (int j = 0; j < 8; ++j) w[j] = tb[buf][vs + j][oc];
            *(bf16x8*)(out + (size_t)(cc + oc) * R + rr + vs) = w;  // 16B store
        }
    };

    loadcvt(0, rrA, ccA);
    __syncthreads();
    loadcvt(1, rrB, ccB);   // tile-B loads fly under tile-A's LDS reads/stores
    storeT(0, rrA, ccA);
    __syncthreads();
    storeT(1, rrB, ccB);
}

// ---------------- FFN1: inter = silu(x@WgT') * (x@WuT') ----------------
// BM=64, BN=64(G)+64(U), BK=32, 32x32x16 MFMA, 4 waves 2x2 (each 32r x 32c of G AND U).
// 4-buf depth-3 counted-vmcnt pipeline (3 loads/stage, vmcnt(6)). 48 KB -> 3 blocks/CU.
// Tile-table grid: only live tiles dispatched; XCD-chunked.
__global__ __launch_bounds__(256) void ffn1_kernel(
    const __bf16* __restrict__ xb, const int* __restrict__ rtok,
    const __bf16* __restrict__ wgT, const __bf16* __restrict__ wuT,
    const int* __restrict__ tiles, __bf16* __restrict__ inter)
{
    // grid 1584 = 22 stripes x 72 tiles; XCD chunks of 198
    const int n  = blockIdx.x;
    const int nn = (n & 7) * 198 + (n >> 3);
    const int i0 = (nn / TILES_MAX) * 64;      // stripe 0..21
    const int tv = tiles[nn % TILES_MAX];
    if (tv < 0) return;
    const int e = tv >> 16;
    const int rowbase = tv & 0xFFFF;

    __shared__ __align__(16) __bf16 sA[4][64][32];  // 16 KB
    __shared__ __align__(16) __bf16 sG[4][64][32];  // 16 KB
    __shared__ __align__(16) __bf16 sU[4][64][32];  // 16 KB -> 48 KB

    const int lane = threadIdx.x & 63;
    const int wid  = threadIdx.x >> 6;
    const int wr = wid >> 1, wc = wid & 1;
    const int l31 = lane & 31;
    const int kg  = lane >> 5;                 // k-half 0/1

    // staging: gload16 covers 16 rows x 64B; lane: row = lane>>2, slot = lane&3.
    // slot s at row R holds global chunk s ^ ((R>>1)&3)  (involution).
    const int r16 = lane >> 2;
    const int cz  = (((lane & 3) ^ ((r16 >> 1) & 3)) * 8);
    const int rowA = rowbase + wid * 16 + r16;
    const int tokp = rtok[rowA];
    const int src  = tokp ? (tokp - 1) : T_TOKENS;     // pad rows -> zero row
    const __bf16* A0 = xb + (size_t)src * HID + cz;
    const size_t wb = (size_t)e * ISZ * HID + (size_t)(i0 + wid * 16 + r16) * HID + cz;
    const __bf16* G0 = wgT + wb;
    const __bf16* U0 = wuT + wb;

    f32x16 accG, accU;
    #pragma unroll
    for (int r = 0; r < 16; ++r) { accG[r] = 0.f; accU[r] = 0.f; }

    auto stage = [&](int b, int k0) {   // 3 gload16 per wave
        gload16(A0 + k0, &sA[b][wid * 16][0]);
        gload16(G0 + k0, &sG[b][wid * 16][0]);
        gload16(U0 + k0, &sU[b][wid * 16][0]);
    };
    auto compute = [&](int b) {
        #pragma unroll
        for (int s = 0; s < 2; ++s) {
            const int ch = ((2 * s + kg) ^ ((l31 >> 1) & 3)) * 8;
            bf16x8 a_ = *(const bf16x8*)&sA[b][wr * 32 + l31][ch];
            bf16x8 g_ = *(const bf16x8*)&sG[b][wc * 32 + l31][ch];
            bf16x8 u_ = *(const bf16x8*)&sU[b][wc * 32 + l31][ch];
            __builtin_amdgcn_s_setprio(1);
            accG = __builtin_amdgcn_mfma_f32_32x32x16_bf16(a_, g_, accG, 0, 0, 0);
            accU = __builtin_amdgcn_mfma_f32_32x32x16_bf16(a_, u_, accU, 0, 0, 0);
            __builtin_amdgcn_s_setprio(0);
        }
    };

    const int nIter = HID / 32;   // 32
    stage(0, 0);
    stage(1, 32);
    stage(2, 64);
    PIPE_BARRIER(6)               // stage0 landed; stages 1,2 (6 loads) in flight
    for (int i = 0; i < nIter; ++i) {
        int ks = (i + 3 < nIter) ? (i + 3) * 32 : 0;   // clamped dead stage keeps counts uniform
        stage((i + 3) & 3, ks);
        compute(i & 3);
        PIPE_BARRIER(6)           // stage(i+1) landed; newest 2 stages in flight
    }

    // epilogue: silu(G)*U -> bf16 inter (D: col = lane&31, row = (r&3)+8*(r>>2)+4*kg)
    const int base_row = rowbase + wr * 32;
    #pragma unroll
    for (int r = 0; r < 16; ++r) {
        float g = accG[r];
        float u = accU[r];
        float v = g / (1.0f + __expf(-g)) * u;
        int row = base_row + (r & 3) + 8 * (r >> 2) + 4 * kg;
        inter[(size_t)row * ISZ + i0 + wc * 32 + l31] = (__bf16)v;
    }
}

// ---------------- FFN2: y[row] = rwt[row] * (inter[row] @ WdT')  (no atomics) ----------------
// BM=64, BN=64, BK=32, 4 waves 2x2 (each 32x32). 4-buf depth-3, vmcnt(4). 32 KB -> 5 blocks/CU.
__global__ __launch_bounds__(256) void ffn2_kernel(
    const __bf16* __restrict__ inter, const __bf16* __restrict__ wdT,
    const float* __restrict__ rwt, const int* __restrict__ tiles,
    float* __restrict__ y)
{
    // grid 1152 = 16 stripes x 72 tiles; XCD chunks of 144
    const int n  = blockIdx.x;
    const int nn = (n & 7) * 144 + (n >> 3);
    const int n0 = (nn / TILES_MAX) * 64;      // stripe 0..15
    const int tv = tiles[nn % TILES_MAX];
    if (tv < 0) return;
    const int e = tv >> 16;
    const int rowbase = tv & 0xFFFF;

    __shared__ __align__(16) __bf16 sA[4][64][32];  // 16 KB
    __shared__ __align__(16) __bf16 sB[4][64][32];  // 16 KB -> 32 KB

    const int lane = threadIdx.x & 63;
    const int wid  = threadIdx.x >> 6;
    const int wr = wid >> 1, wc = wid & 1;
    const int l31 = lane & 31;
    const int kg  = lane >> 5;

    const int r16 = lane >> 2;
    const int cz  = (((lane & 3) ^ ((r16 >> 1) & 3)) * 8);
    const __bf16* A0 = inter + (size_t)(rowbase + wid * 16 + r16) * ISZ + cz;
    const __bf16* B0 = wdT + (size_t)e * HID * ISZ + (size_t)(n0 + wid * 16 + r16) * ISZ + cz;

    f32x16 acc;
    #pragma unroll
    for (int r = 0; r < 16; ++r) acc[r] = 0.f;

    auto stage = [&](int b, int k0) {   // 2 gload16 per wave
        gload16(A0 + k0, &sA[b][wid * 16][0]);
        gload16(B0 + k0, &sB[b][wid * 16][0]);
    };
    auto compute = [&](int b) {
        #pragma unroll
        for (int s = 0; s < 2; ++s) {
            const int ch = ((2 * s + kg) ^ ((l31 >> 1) & 3)) * 8;
            bf16x8 a_ = *(const bf16x8*)&sA[b][wr * 32 + l31][ch];
            bf16x8 b_ = *(const bf16x8*)&sB[b][wc * 32 + l31][ch];
            __builtin_amdgcn_s_setprio(1);
            acc = __builtin_amdgcn_mfma_f32_32x32x16_bf16(a_, b_, acc, 0, 0, 0);
            __builtin_amdgcn_s_setprio(0);
        }
    };

    const int nIter = ISZ / 32;   // 44
    stage(0, 0);
    stage(1, 32);
    stage(2, 64);
    PIPE_BARRIER(4)
    for (int i = 0; i < nIter; ++i) {
        int ks = (i + 3 < nIter) ? (i + 3) * 32 : 0;
        stage((i + 3) & 3, ks);
        compute(i & 3);
        PIPE_BARRIER(4)
    }

    const int base_row = rowbase + wr * 32;
    const int col = n0 + wc * 32 + l31;
    #pragma unroll
    for (int r = 0; r < 16; ++r) {
        int row = base_row + (r & 3) + 8 * (r >> 2) + 4 * kg;
        y[(size_t)row * HID + col] = rwt[row] * acc[r];
    }
}

// ---------------- Combine: out[t] = y[row0(t)] + y[row1(t)] ----------------
__global__ __launch_bounds__(256) void combine_kernel(
    const float* __restrict__ y, const int* __restrict__ tok2row, float* __restrict__ out)
{
    const int idx = blockIdx.x * 256 + threadIdx.x;
    const int t = idx >> 8;
    const int c = (idx & 255) * 4;
    const int r0 = tok2row[t * 2];
    const int r1 = tok2row[t * 2 + 1];
    float4 a = *(const float4*)(y + (size_t)r0 * HID + c);
    float4 b = *(const float4*)(y + (size_t)r1 * HID + c);
    float4 o = {a.x + b.x, a.y + b.y, a.z + b.z, a.w + b.w};
    *(float4*)(out + (size_t)t * HID + c) = o;
}

extern "C" void kernel_launch(void* const* d_in, const int* in_sizes, int n_in,
                              void* d_out, int out_size, void* d_ws, size_t ws_size,
                              hipStream_t stream) {
    const float* x  = (const float*)d_in[0];
    const float* gw = (const float*)d_in[1];
    const float* wg = (const float*)d_in[2];
    const float* wu = (const float*)d_in[3];
    const float* wd = (const float*)d_in[4];
    float* out = (float*)d_out;

    char* ws = (char*)d_ws;
    int*    tiles   = (int*)(ws + 64);           // 72 ints
    int*    sel     = (int*)(ws + 1024);         // 4096 ints
    float*  wtp     = (float*)(ws + 17408);      // 4096 f32
    int*    rtok    = (int*)(ws + 33792);        // 4608 ints
    float*  rwt     = (float*)(ws + 52224);      // 4608 f32
    int*    tok2row = (int*)(ws + 70656);        // 4096 ints -> ends 87040
    __bf16* xb      = (__bf16*)(ws + 87040);     // 2049*1024 bf16 = 4.20 MB
    __bf16* inter   = (__bf16*)(ws + 4283648);   // 4608*1408 bf16 = 12.98 MB
    __bf16* wgT     = (__bf16*)(ws + 17260032);  // 23.07 MB
    __bf16* wuT     = (__bf16*)(ws + 40328704);  // 23.07 MB
    __bf16* wdT     = (__bf16*)(ws + 63397376);  // 23.07 MB -> ends 86.5 MB
    float*  y       = (float*)wgT;               // alias: wgT dead after ffn1 (18.9 MB <= 23.07)

    // one merged zero-fill: tiles + rtok (sentinel 0 = pad) + rwt + headers
    hipMemsetAsync(ws, 0, 87040, stream);

    tcvt_all_kernel<<<dim3(ISZ / 128, HID / 64, 24), 256, 0, stream>>>(wg, wu, wd, wgT, wuT, wdT);

    router_kernel<<<T_TOKENS / 4, 256, 0, stream>>>(x, gw, sel, wtp, xb);
    scan_assign_kernel<<<1, 256, 0, stream>>>(tiles, sel, wtp, rtok, rwt, tok2row);

    ffn1_kernel<<<22 * TILES_MAX, 256, 0, stream>>>(xb, rtok, wgT, wuT, tiles, inter);  // 1584
    ffn2_kernel<<<16 * TILES_MAX, 256, 0, stream>>>(inter, wdT, rwt, tiles, y);         // 1152
    combine_kernel<<<(T_TOKENS * HID / 4) / 256, 256, 0, stream>>>(y, tok2row, out);
}